// Round 2
// baseline (415.231 us; speedup 1.0000x reference)
//
#include <hip/hip_runtime.h>
#include <math.h>

// Problem constants
#define BB    8192
#define NN    512
#define KKN   8
#define HH    1024
#define OUTD  (NN * (2 * KKN + 1))   // 8704

typedef unsigned short ushort_t;
typedef __bf16 bf16x8 __attribute__((ext_vector_type(8)));
typedef float  f32x16 __attribute__((ext_vector_type(16)));
typedef float  f32x4  __attribute__((ext_vector_type(4)));

// float -> bf16 round-to-nearest-even
__device__ inline ushort_t f2bf(float f) {
    unsigned int u = __float_as_uint(f);
    unsigned int r = (u + 0x7fffu + ((u >> 16) & 1u)) >> 16;
    return (ushort_t)r;
}
__device__ inline float bf2f(ushort_t u) {
    return __uint_as_float(((unsigned int)u) << 16);
}

// 5-op tanh: 1 - 2/(e^{2x}+1). Saturates correctly for |x| large.
__device__ inline float fast_tanh(float x) {
    float t = __expf(x + x);
    return fmaf(-2.f, __builtin_amdgcn_rcpf(t + 1.f), 1.f);
}

// ---------------------------------------------------------------------------
// conv_v: a0b[b][n] = bf16(v_in[b][n] - 0.5), n in [0,512). v_in rows are 1024.
// ---------------------------------------------------------------------------
__global__ __launch_bounds__(256) void conv_v(
    const float* __restrict__ v_in, ushort_t* __restrict__ a0b)
{
    int t = blockIdx.x * 256 + threadIdx.x;          // 0 .. B*512/2-1
    int e0 = t * 2;
    int b = e0 >> 9;
    int n = e0 & 511;
    const float2 v = *(const float2*)(v_in + (size_t)b * (2 * NN) + n);
    ushort_t* o = a0b + (size_t)b * NN + n;
    o[0] = f2bf(v.x - 0.5f);
    o[1] = f2bf(v.y - 0.5f);
}

// ---------------------------------------------------------------------------
// transpose_cvt: W (Kd x Nd fp32 row-major) -> WT (Nd x Kd bf16 row-major)
// PERM: out-row r is remapped to (r%17)*512 + r/17 (plane-major net layout)
// ---------------------------------------------------------------------------
template <bool PERM>
__global__ __launch_bounds__(256) void transpose_cvt(
    const float* __restrict__ W, ushort_t* __restrict__ WT, int Kd, int Nd)
{
    __shared__ float tile[32][33];
    const int bx = blockIdx.x * 32;   // n base
    const int by = blockIdx.y * 32;   // k base
    const int tx = threadIdx.x;       // 0..31
    const int ty = threadIdx.y;       // 0..7
#pragma unroll
    for (int i = 0; i < 32; i += 8)
        tile[ty + i][tx] = W[(size_t)(by + ty + i) * Nd + bx + tx];
    __syncthreads();
#pragma unroll
    for (int i = 0; i < 32; i += 8) {
        int r = bx + ty + i;
        if (PERM) r = (r % 17) * 512 + (r / 17);
        WT[(size_t)r * Kd + by + tx] = f2bf(tile[tx][ty + i]);
    }
}

// ---------------------------------------------------------------------------
// bf16 MFMA GEMM, 32x32x16 shape: C = bf16(tanh(A @ B + bias))  (128x128 tile)
// Kept for GEMM1/GEMM2 (small-N shapes need 2+ blocks/CU; proven).
// ---------------------------------------------------------------------------
template <bool PERM_BIAS>
__global__ __launch_bounds__(256) void gemm_bt_tanh(
    const ushort_t* __restrict__ A,
    const ushort_t* __restrict__ BT,
    const float* __restrict__ bias,
    ushort_t* __restrict__ C,
    int N_, int K)
{
    __shared__ __align__(16) ushort_t sA[128 * 32];   // [row][k-chunk swizzled] 8 KB
    __shared__ __align__(16) ushort_t sB[128 * 32];

    const int t    = threadIdx.x;
    const int lane = t & 63;
    const int w    = t >> 6;
    const int wy   = w >> 1;
    const int wx   = w & 1;
    const int l31  = lane & 31;
    const int h    = lane >> 5;       // k-half within fragment

    const int brow = blockIdx.y * 128;
    const int bcol = blockIdx.x * 128;

    f32x16 acc[2][2] = {};

    const int cwb = (t & ~63);       // wave-uniform chunk base

    int rS[2], gS[2];
#pragma unroll
    for (int p = 0; p < 2; ++p) {
        const int c = p * 256 + t;
        rS[p] = c >> 2;
        gS[p] = ((c & 3) - (rS[p] >> 1)) & 3;
    }

    int offA[2][2], offB[2][2];
#pragma unroll
    for (int ks = 0; ks < 2; ++ks)
#pragma unroll
        for (int ti = 0; ti < 2; ++ti) {
            const int rA = wy * 64 + ti * 32 + l31;
            offA[ks][ti] = rA * 32 + ((2 * ks + h + (rA >> 1)) & 3) * 8;
            const int rB = wx * 64 + ti * 32 + l31;
            offB[ks][ti] = rB * 32 + ((2 * ks + h + (rB >> 1)) & 3) * 8;
        }

    for (int k0 = 0; k0 < K; k0 += 32) {
        __syncthreads();
#pragma unroll
        for (int p = 0; p < 2; ++p) {
            const int cb = p * 256 + cwb;
            const ushort_t* ga = A  + (size_t)(brow + rS[p]) * K + k0 + gS[p] * 8;
            const ushort_t* gb = BT + (size_t)(bcol + rS[p]) * K + k0 + gS[p] * 8;
            __builtin_amdgcn_global_load_lds(
                (const __attribute__((address_space(1))) void*)ga,
                (__attribute__((address_space(3))) void*)(sA + (size_t)cb * 8), 16, 0, 0);
            __builtin_amdgcn_global_load_lds(
                (const __attribute__((address_space(1))) void*)gb,
                (__attribute__((address_space(3))) void*)(sB + (size_t)cb * 8), 16, 0, 0);
        }
        __syncthreads();

#pragma unroll
        for (int ks = 0; ks < 2; ++ks) {
            const bf16x8 a0 = *(const bf16x8*)(sA + offA[ks][0]);
            const bf16x8 a1 = *(const bf16x8*)(sA + offA[ks][1]);
            const bf16x8 b0 = *(const bf16x8*)(sB + offB[ks][0]);
            const bf16x8 b1 = *(const bf16x8*)(sB + offB[ks][1]);
            acc[0][0] = __builtin_amdgcn_mfma_f32_32x32x16_bf16(a0, b0, acc[0][0], 0, 0, 0);
            acc[0][1] = __builtin_amdgcn_mfma_f32_32x32x16_bf16(a0, b1, acc[0][1], 0, 0, 0);
            acc[1][0] = __builtin_amdgcn_mfma_f32_32x32x16_bf16(a1, b0, acc[1][0], 0, 0, 0);
            acc[1][1] = __builtin_amdgcn_mfma_f32_32x32x16_bf16(a1, b1, acc[1][1], 0, 0, 0);
        }
    }

#pragma unroll
    for (int tj = 0; tj < 2; ++tj) {
        const int col = bcol + wx * 64 + tj * 32 + l31;
        const int bidx = PERM_BIAS ? ((col & 511) * 17 + (col >> 9)) : col;
        const float bv = bias[bidx];
#pragma unroll
        for (int ti = 0; ti < 2; ++ti) {
            const int rb = brow + wy * 64 + ti * 32 + 4 * h;
#pragma unroll
            for (int reg = 0; reg < 16; ++reg) {
                const int row = rb + (reg & 3) + 8 * (reg >> 2);
                C[(size_t)row * N_ + col] = f2bf(fast_tanh(acc[ti][tj][reg] + bv));
            }
        }
    }
}

// ---------------------------------------------------------------------------
// R7: GEMM3 kernel — 256x256 tile, 512 thr = 8 waves (2M x 4N), ring-of-4
// K-slice pipeline with counted vmcnt (unchanged from R6), but MFMA switched
// to 32x32x16 so the epilogue stores are FULL-LINE coalesced (col = l31 ->
// 32 lanes x 2B = 64B). R6's 16x16 epilogue wrote 32B half-lines: WRITE_SIZE
// 265MB (~2x C) + RMW FETCH +120MB. This kills that.
//   - Per wave: 128x64 out = 4m x 2n tiles of 32x32; acc = 8 x f32x16.
//   - Per K-slice (32): 12 ds_read_b128 + 16 MFMA in 2 phases (bR reused).
//   - Swizzle: LDS slot j of row r holds global chunk j ^ ((r>>1)&3)
//     (involution, applied on pre-swizzled global src + read addr, rule #21).
//     32-row fragment reads are ~4-way banked (16B-granular swizzle floor);
//     accepted — proven tolerable in the 128^2 kernel.
//   - Staging 3 slices ahead; boundary vmcnt(8) keeps 2 slices in flight;
//     epilogue drains 8->4->0. Ledger as R6 (verified).
// ---------------------------------------------------------------------------
#define SLOT_U (256 * 32)   // ushorts per ring slot (16 KiB)

__device__ __forceinline__ void stage16(
    const ushort_t* __restrict__ gsrc, ushort_t* lds_dst)
{
    __builtin_amdgcn_global_load_lds(
        (const __attribute__((address_space(1))) void*)gsrc,
        (__attribute__((address_space(3))) void*)lds_dst, 16, 0, 0);
}

template <bool PERM_BIAS>
__global__ __launch_bounds__(512, 2) void gemm3_bt_tanh_256(
    const ushort_t* __restrict__ A,
    const ushort_t* __restrict__ BT,
    const float* __restrict__ bias,
    ushort_t* __restrict__ C,
    int N_, int K)
{
    __shared__ __align__(16) ushort_t sA[4 * SLOT_U];   // 64 KiB
    __shared__ __align__(16) ushort_t sB[4 * SLOT_U];   // 64 KiB

    const int t    = threadIdx.x;
    const int lane = t & 63;
    const int w    = t >> 6;
    const int wy   = w >> 2;        // 0..1  (M half: 128 rows)
    const int wx   = w & 3;         // 0..3  (N quarter: 64 cols)
    const int l31  = lane & 31;
    const int h    = lane >> 5;     // k-half within fragment

    // XCD-aware bijective swizzle (nwg % 8 == 0 in all tiers): XCD k gets a
    // contiguous run of tiles -> A-panels (2MB) L2-resident per XCD.
    const int gx  = gridDim.x;
    const int nwg = gx * gridDim.y;
    int id = blockIdx.y * gx + blockIdx.x;
    id = (id & 7) * (nwg >> 3) + (id >> 3);
    const int brow = (id / gx) * 256;
    const int bcol = (id % gx) * 256;

    f32x16 acc[4][2] = {};

    // staging: thread t covers row rL = t>>2 of a 128-row half, LDS chunk
    // slot j = t&3 holding global chunk g = j ^ ((rL>>1)&3).
    const int rL  = t >> 2;
    const int g8  = (((t & 3) ^ ((t >> 3) & 3)) << 3);   // elem offset of chunk
    const int wbU = (t & ~63) * 8;                       // wave-uniform base (ushorts)
    const size_t rowA0 = (size_t)(brow + rL) * K;
    const size_t rowA1 = (size_t)(brow + 128 + rL) * K;
    const size_t rowB0 = (size_t)(bcol + rL) * K;
    const size_t rowB1 = (size_t)(bcol + 128 + rL) * K;

    // fragment read offsets (ushort units within a slot), swizzled.
    // desired global chunk for (ks,h) is 2*ks+h; LDS slot = g ^ ((r>>1)&3).
    int offA[4][2], offB[2][2];
#pragma unroll
    for (int m = 0; m < 4; ++m) {
        const int rA = wy * 128 + m * 32 + l31;
#pragma unroll
        for (int ks = 0; ks < 2; ++ks)
            offA[m][ks] = rA * 32 + (((2 * ks + h) ^ ((rA >> 1) & 3)) << 3);
    }
#pragma unroll
    for (int n = 0; n < 2; ++n) {
        const int rB = wx * 64 + n * 32 + l31;
#pragma unroll
        for (int ks = 0; ks < 2; ++ks)
            offB[n][ks] = rB * 32 + (((2 * ks + h) ^ ((rB >> 1) & 3)) << 3);
    }

    const int NT = K >> 5;   // K-slices of 32 (K=1024 -> 32; NT >= 4 required)

    // prologue: stage slices 0,1,2 (12 issues); vmcnt(8) -> slice 0 landed.
#pragma unroll
    for (int sp = 0; sp < 3; ++sp) {
        const int kk = sp << 5;
        ushort_t* dA = sA + sp * SLOT_U + wbU;
        ushort_t* dB = sB + sp * SLOT_U + wbU;
        stage16(A  + rowA0 + kk + g8, dA);
        stage16(BT + rowB0 + kk + g8, dB);
        stage16(A  + rowA1 + kk + g8, dA + 4096);
        stage16(BT + rowB1 + kk + g8, dB + 4096);
    }
    asm volatile("s_waitcnt vmcnt(8)" ::: "memory");
    __builtin_amdgcn_s_barrier();

    for (int s = 0; s < NT; ++s) {
        const ushort_t* sAs = sA + (s & 3) * SLOT_U;
        const ushort_t* sBs = sB + (s & 3) * SLOT_U;
        const int sp = s + 3;
        const int kk = sp << 5;
        ushort_t* dA = sA + (sp & 3) * SLOT_U + wbU;
        ushort_t* dB = sB + (sp & 3) * SLOT_U + wbU;

        // ---- phase A: read B (4 b128) + A m0,m1 (4 b128); stage pair 0 ----
        bf16x8 bR[2][2], aR[2][2];
#pragma unroll
        for (int n = 0; n < 2; ++n)
#pragma unroll
            for (int ks = 0; ks < 2; ++ks)
                bR[n][ks] = *(const bf16x8*)(sBs + offB[n][ks]);
#pragma unroll
        for (int m = 0; m < 2; ++m)
#pragma unroll
            for (int ks = 0; ks < 2; ++ks)
                aR[m][ks] = *(const bf16x8*)(sAs + offA[m][ks]);
        if (sp < NT) {
            stage16(A  + rowA0 + kk + g8, dA);
            stage16(BT + rowB0 + kk + g8, dB);
        }
        __builtin_amdgcn_s_barrier();
        __builtin_amdgcn_s_setprio(1);
#pragma unroll
        for (int ks = 0; ks < 2; ++ks)
#pragma unroll
            for (int m = 0; m < 2; ++m)
#pragma unroll
                for (int n = 0; n < 2; ++n)
                    acc[m][n] = __builtin_amdgcn_mfma_f32_32x32x16_bf16(
                        aR[m][ks], bR[n][ks], acc[m][n], 0, 0, 0);
        __builtin_amdgcn_s_setprio(0);
        __builtin_amdgcn_s_barrier();

        // ---- phase B: read A m2,m3 (4 b128); stage pair 1; bR reused ----
#pragma unroll
        for (int m = 0; m < 2; ++m)
#pragma unroll
            for (int ks = 0; ks < 2; ++ks)
                aR[m][ks] = *(const bf16x8*)(sAs + offA[2 + m][ks]);
        if (sp < NT) {
            stage16(A  + rowA1 + kk + g8, dA + 4096);
            stage16(BT + rowB1 + kk + g8, dB + 4096);
        }
        __builtin_amdgcn_s_barrier();
        __builtin_amdgcn_s_setprio(1);
#pragma unroll
        for (int ks = 0; ks < 2; ++ks)
#pragma unroll
            for (int m = 0; m < 2; ++m)
#pragma unroll
                for (int n = 0; n < 2; ++n)
                    acc[2 + m][n] = __builtin_amdgcn_mfma_f32_32x32x16_bf16(
                        aR[m][ks], bR[n][ks], acc[2 + m][n], 0, 0, 0);
        __builtin_amdgcn_s_setprio(0);

        // ---- slice boundary: drain slice s+1 only, keep s+2/s+3 in flight ----
        if (s < NT - 3)       asm volatile("s_waitcnt vmcnt(8)" ::: "memory");
        else if (s == NT - 3) asm volatile("s_waitcnt vmcnt(4)" ::: "memory");
        else if (s == NT - 2) asm volatile("s_waitcnt vmcnt(0)" ::: "memory");
        __builtin_amdgcn_s_barrier();
    }

    // epilogue: 32x32 C/D mapping col=lane&31, row=(reg&3)+8*(reg>>2)+4*h
    // [m74/m101 verified]. 32 lanes x 2B = full 64B line per store.
#pragma unroll
    for (int n = 0; n < 2; ++n) {
        const int col = bcol + wx * 64 + n * 32 + l31;
        const int bidx = PERM_BIAS ? ((col & 511) * 17 + (col >> 9)) : col;
        const float bv = bias[bidx];
#pragma unroll
        for (int m = 0; m < 4; ++m) {
            const int rb = brow + wy * 128 + m * 32 + 4 * h;
#pragma unroll
            for (int reg = 0; reg < 16; ++reg) {
                const int row = rb + (reg & 3) + 8 * (reg >> 2);
                C[(size_t)row * N_ + col] = f2bf(fast_tanh(acc[m][n][reg] + bv));
            }
        }
    }
}

// ---------------------------------------------------------------------------
// Spline postprocess, plane-major net layout: net[b][p*512 + n] holds value
// p of unit n (p<9: h_net, p>=9: w_net). One block per batch row, 256
// threads; thread t handles units 2t, 2t+1 via dword plane loads (coalesced).
// ---------------------------------------------------------------------------
__global__ __launch_bounds__(256) void spline_post(
    const ushort_t* __restrict__ net,   // rows x OUTD bf16, plane-major
    const float* __restrict__ v_in,     // rows x 2N
    const float* __restrict__ ld_in,    // rows
    float* __restrict__ v_out,          // rows x 2N
    float* __restrict__ ld_out)         // rows
{
    const int b = blockIdx.x;
    const int t = threadIdx.x;          // 0..255

    unsigned int pl[17];
    const ushort_t* base = net + (size_t)b * OUTD + 2 * t;
#pragma unroll
    for (int p = 0; p < 17; ++p)
        pl[p] = *(const unsigned int*)(base + p * 512);

    {
        const float2 vp = *(const float2*)(v_in + (size_t)b * (2 * NN) + 2 * t);
        *(float2*)(v_out + (size_t)b * (2 * NN) + 2 * t) = vp;
    }
    const float2 va2 = *(const float2*)(v_in + (size_t)b * (2 * NN) + NN + 2 * t);

    float vact[2];
    float lt_sum = 0.f;
#pragma unroll 1
    for (int u = 0; u < 2; ++u) {
        const int sh = u * 16;
        float t17[17];
#pragma unroll
        for (int p = 0; p < 17; ++p)
            t17[p] = bf2f((ushort_t)(pl[p] >> sh));

        float m = t17[9];
#pragma unroll
        for (int i = 10; i < 17; i++) m = fmaxf(m, t17[i]);
        float wn[8], wsum = 0.f;
#pragma unroll
        for (int i = 0; i < 8; i++) { wn[i] = __expf(t17[9 + i] - m); wsum += wn[i]; }
        const float winv = 1.f / wsum;
#pragma unroll
        for (int i = 0; i < 8; i++) wn[i] *= winv;

        float eh[9];
#pragma unroll
        for (int i = 0; i < 9; i++) eh[i] = __expf(t17[i]);
        float denom = 0.f;
#pragma unroll
        for (int k = 0; k < 8; k++) denom += 0.5f * wn[k] * (eh[k] + eh[k + 1]);
        const float dinv = 1.f / denom;
        float hn[9];
#pragma unroll
        for (int i = 0; i < 9; i++) hn[i] = eh[i] * dinv;

        float kx[9], ky[9];
        kx[0] = 0.f; ky[0] = 0.f;
#pragma unroll
        for (int k = 0; k < 8; k++) {
            kx[k + 1] = kx[k] + wn[k];
            ky[k + 1] = ky[k] + 0.5f * wn[k] * (hn[k] + hn[k + 1]);
        }

        const float va = (u == 0) ? va2.x : va2.y;
        int cnt = 0;
#pragma unroll
        for (int j = 0; j < 9; j++) cnt += (kx[j] < va) ? 1 : 0;
        int k = cnt - 1;
        k = k < 0 ? 0 : (k > KKN - 1 ? KKN - 1 : k);

        const float wseg = wn[k];
        const float hlo = hn[k], hhi = hn[k + 1];
        const float xlo = kx[k], ylo = ky[k];
        const float alpha = (va - xlo) / wseg;
        vact[u] = ylo + alpha * hlo * wseg + 0.5f * alpha * alpha * (hhi - hlo) * wseg;
        lt_sum += __logf(hlo + alpha * (hhi - hlo));
    }

    *(float2*)(v_out + (size_t)b * (2 * NN) + NN + 2 * t) = make_float2(vact[0], vact[1]);

    __shared__ float wred[4];
#pragma unroll
    for (int o = 32; o > 0; o >>= 1) lt_sum += __shfl_down(lt_sum, o, 64);
    if ((t & 63) == 0) wred[t >> 6] = lt_sum;
    __syncthreads();
    if (t == 0)
        ld_out[b] = ld_in[b] - (wred[0] + wred[1] + wred[2] + wred[3]);
}

// ---------------------------------------------------------------------------
extern "C" void kernel_launch(void* const* d_in, const int* in_sizes, int n_in,
                              void* d_out, int out_size, void* d_ws, size_t ws_size,
                              hipStream_t stream)
{
    const float* v_in = (const float*)d_in[0];   // B x 2N
    const float* ld   = (const float*)d_in[1];   // B x 1
    const float* W1   = (const float*)d_in[2];   // N x H
    const float* b1   = (const float*)d_in[3];   // H
    const float* W2   = (const float*)d_in[4];   // H x H
    const float* b2   = (const float*)d_in[5];   // H
    const float* W3   = (const float*)d_in[6];   // H x OUTD
    const float* b3   = (const float*)d_in[7];   // OUTD

    float* out    = (float*)d_out;
    float* v_out  = out;                           // B*2N
    float* ld_out = out + (size_t)BB * (2 * NN);   // B

    // Workspace tiers (R3-verified: full tier 172Mi fits):
    //   [0, region)       chunk net buffer (plane-major); a0b + x1b alias here
    //   [region, +16Mi)   x2b ; then W1T (1Mi) W2T (2Mi) W3T (17Mi)
    const size_t Mi = 1048576;
    int    chunk;
    size_t region;
    if      (ws_size >= 172 * Mi) { chunk = 8192; region = 136 * Mi; }
    else if (ws_size >= 104 * Mi) { chunk = 4096; region =  68 * Mi; }
    else if (ws_size >=  70 * Mi) { chunk = 2048; region =  34 * Mi; }
    else                          { chunk = 1024; region =  24 * Mi; }

    char* ws = (char*)d_ws;
    ushort_t* a0b = (ushort_t*)(ws);
    ushort_t* x1b = (ushort_t*)(ws + 8 * Mi);
    ushort_t* netc = (ushort_t*)(ws);                       // chunk buffer
    ushort_t* x2b = (ushort_t*)(ws + region);
    ushort_t* W1T = (ushort_t*)(ws + region + 16 * Mi);
    ushort_t* W2T = (ushort_t*)(ws + region + 17 * Mi);
    ushort_t* W3T = (ushort_t*)(ws + region + 19 * Mi);

    // conversions
    conv_v<<<dim3(BB * NN / 2 / 256), dim3(256), 0, stream>>>(v_in, a0b);
    transpose_cvt<false><<<dim3(HH / 32, NN / 32),   dim3(32, 8), 0, stream>>>(W1, W1T, NN, HH);
    transpose_cvt<false><<<dim3(HH / 32, HH / 32),   dim3(32, 8), 0, stream>>>(W2, W2T, HH, HH);
    transpose_cvt<true ><<<dim3(OUTD / 32, HH / 32), dim3(32, 8), 0, stream>>>(W3, W3T, HH, OUTD);

    // GEMM1: x1 = tanh((v_passive-0.5) @ W1 + b1)   M=8192 N=1024 K=512
    gemm_bt_tanh<false><<<dim3(HH / 128, BB / 128), dim3(256), 0, stream>>>(
        a0b, W1T, b1, x1b, HH, NN);
    // GEMM2: x2 = tanh(x1 @ W2 + b2)                M=8192 N=1024 K=1024
    gemm_bt_tanh<false><<<dim3(HH / 128, BB / 128), dim3(256), 0, stream>>>(
        x1b, W2T, b2, x2b, HH, HH);

    // GEMM3 + spline, chunked (single pass when chunk==8192)
    // R7: 256x256 ring-pipeline kernel, 32x32 MFMA (coalesced 64B stores).
    for (int c = 0; c < BB / chunk; ++c) {
        const ushort_t* xa = x2b + (size_t)c * chunk * HH;
        gemm3_bt_tanh_256<true><<<dim3(OUTD / 256, chunk / 256), dim3(512), 0, stream>>>(
            xa, W3T, b3, netc, OUTD, HH);
        spline_post<<<dim3(chunk), dim3(256), 0, stream>>>(
            netc,
            v_in   + (size_t)c * chunk * (2 * NN),
            ld     + (size_t)c * chunk,
            v_out  + (size_t)c * chunk * (2 * NN),
            ld_out + (size_t)c * chunk);
    }
}

// Round 4
// 393.294 us; speedup vs baseline: 1.0558x; 1.0558x over previous
//
#include <hip/hip_runtime.h>
#include <math.h>

// Problem constants
#define BB    8192
#define NN    512
#define KKN   8
#define HH    1024
#define OUTD  (NN * (2 * KKN + 1))   // 8704

typedef unsigned short ushort_t;
typedef __bf16 bf16x8 __attribute__((ext_vector_type(8)));
typedef float  f32x16 __attribute__((ext_vector_type(16)));
typedef float  f32x4  __attribute__((ext_vector_type(4)));
typedef int    i32x4  __attribute__((ext_vector_type(4)));
typedef float  f32x2v __attribute__((ext_vector_type(2)));

// float -> bf16 round-to-nearest-even
__device__ inline ushort_t f2bf(float f) {
    unsigned int u = __float_as_uint(f);
    unsigned int r = (u + 0x7fffu + ((u >> 16) & 1u)) >> 16;
    return (ushort_t)r;
}
__device__ inline float bf2f(ushort_t u) {
    return __uint_as_float(((unsigned int)u) << 16);
}

// 5-op tanh: 1 - 2/(e^{2x}+1). Saturates correctly for |x| large.
__device__ inline float fast_tanh(float x) {
    float t = __expf(x + x);
    return fmaf(-2.f, __builtin_amdgcn_rcpf(t + 1.f), 1.f);
}

// ---------------------------------------------------------------------------
// conv_v: a0b[b][n] = bf16(v_in[b][n] - 0.5), n in [0,512). v_in rows are 1024.
// ---------------------------------------------------------------------------
__global__ __launch_bounds__(256) void conv_v(
    const float* __restrict__ v_in, ushort_t* __restrict__ a0b)
{
    int t = blockIdx.x * 256 + threadIdx.x;          // 0 .. B*512/2-1
    int e0 = t * 2;
    int b = e0 >> 9;
    int n = e0 & 511;
    const float2 v = *(const float2*)(v_in + (size_t)b * (2 * NN) + n);
    ushort_t* o = a0b + (size_t)b * NN + n;
    o[0] = f2bf(v.x - 0.5f);
    o[1] = f2bf(v.y - 0.5f);
}

// ---------------------------------------------------------------------------
// transpose_cvt: W (Kd x Nd fp32 row-major) -> WT (Nd x Kd bf16 row-major)
// PERM: out-row r is remapped to (r%17)*512 + r/17 (plane-major net layout)
// ---------------------------------------------------------------------------
template <bool PERM>
__global__ __launch_bounds__(256) void transpose_cvt(
    const float* __restrict__ W, ushort_t* __restrict__ WT, int Kd, int Nd)
{
    __shared__ float tile[32][33];
    const int bx = blockIdx.x * 32;   // n base
    const int by = blockIdx.y * 32;   // k base
    const int tx = threadIdx.x;       // 0..31
    const int ty = threadIdx.y;       // 0..7
#pragma unroll
    for (int i = 0; i < 32; i += 8)
        tile[ty + i][tx] = W[(size_t)(by + ty + i) * Nd + bx + tx];
    __syncthreads();
#pragma unroll
    for (int i = 0; i < 32; i += 8) {
        int r = bx + ty + i;
        if (PERM) r = (r % 17) * 512 + (r / 17);
        WT[(size_t)r * Kd + by + tx] = f2bf(tile[tx][ty + i]);
    }
}

// ---------------------------------------------------------------------------
// bf16 MFMA GEMM, 32x32x16 shape: C = bf16(tanh(A @ B + bias))  (128x128 tile)
// Kept for GEMM1/GEMM2 (small-N shapes need 2+ blocks/CU; proven).
// ---------------------------------------------------------------------------
template <bool PERM_BIAS>
__global__ __launch_bounds__(256) void gemm_bt_tanh(
    const ushort_t* __restrict__ A,
    const ushort_t* __restrict__ BT,
    const float* __restrict__ bias,
    ushort_t* __restrict__ C,
    int N_, int K)
{
    __shared__ __align__(16) ushort_t sA[128 * 32];   // [row][k-chunk swizzled] 8 KB
    __shared__ __align__(16) ushort_t sB[128 * 32];

    const int t    = threadIdx.x;
    const int lane = t & 63;
    const int w    = t >> 6;
    const int wy   = w >> 1;
    const int wx   = w & 1;
    const int l31  = lane & 31;
    const int h    = lane >> 5;       // k-half within fragment

    const int brow = blockIdx.y * 128;
    const int bcol = blockIdx.x * 128;

    f32x16 acc[2][2] = {};

    const int cwb = (t & ~63);       // wave-uniform chunk base

    int rS[2], gS[2];
#pragma unroll
    for (int p = 0; p < 2; ++p) {
        const int c = p * 256 + t;
        rS[p] = c >> 2;
        gS[p] = ((c & 3) - (rS[p] >> 1)) & 3;
    }

    int offA[2][2], offB[2][2];
#pragma unroll
    for (int ks = 0; ks < 2; ++ks)
#pragma unroll
        for (int ti = 0; ti < 2; ++ti) {
            const int rA = wy * 64 + ti * 32 + l31;
            offA[ks][ti] = rA * 32 + ((2 * ks + h + (rA >> 1)) & 3) * 8;
            const int rB = wx * 64 + ti * 32 + l31;
            offB[ks][ti] = rB * 32 + ((2 * ks + h + (rB >> 1)) & 3) * 8;
        }

    for (int k0 = 0; k0 < K; k0 += 32) {
        __syncthreads();
#pragma unroll
        for (int p = 0; p < 2; ++p) {
            const int cb = p * 256 + cwb;
            const ushort_t* ga = A  + (size_t)(brow + rS[p]) * K + k0 + gS[p] * 8;
            const ushort_t* gb = BT + (size_t)(bcol + rS[p]) * K + k0 + gS[p] * 8;
            __builtin_amdgcn_global_load_lds(
                (const __attribute__((address_space(1))) void*)ga,
                (__attribute__((address_space(3))) void*)(sA + (size_t)cb * 8), 16, 0, 0);
            __builtin_amdgcn_global_load_lds(
                (const __attribute__((address_space(1))) void*)gb,
                (__attribute__((address_space(3))) void*)(sB + (size_t)cb * 8), 16, 0, 0);
        }
        __syncthreads();

#pragma unroll
        for (int ks = 0; ks < 2; ++ks) {
            const bf16x8 a0 = *(const bf16x8*)(sA + offA[ks][0]);
            const bf16x8 a1 = *(const bf16x8*)(sA + offA[ks][1]);
            const bf16x8 b0 = *(const bf16x8*)(sB + offB[ks][0]);
            const bf16x8 b1 = *(const bf16x8*)(sB + offB[ks][1]);
            acc[0][0] = __builtin_amdgcn_mfma_f32_32x32x16_bf16(a0, b0, acc[0][0], 0, 0, 0);
            acc[0][1] = __builtin_amdgcn_mfma_f32_32x32x16_bf16(a0, b1, acc[0][1], 0, 0, 0);
            acc[1][0] = __builtin_amdgcn_mfma_f32_32x32x16_bf16(a1, b0, acc[1][0], 0, 0, 0);
            acc[1][1] = __builtin_amdgcn_mfma_f32_32x32x16_bf16(a1, b1, acc[1][1], 0, 0, 0);
        }
    }

#pragma unroll
    for (int tj = 0; tj < 2; ++tj) {
        const int col = bcol + wx * 64 + tj * 32 + l31;
        const int bidx = PERM_BIAS ? ((col & 511) * 17 + (col >> 9)) : col;
        const float bv = bias[bidx];
#pragma unroll
        for (int ti = 0; ti < 2; ++ti) {
            const int rb = brow + wy * 64 + ti * 32 + 4 * h;
#pragma unroll
            for (int reg = 0; reg < 16; ++reg) {
                const int row = rb + (reg & 3) + 8 * (reg >> 2);
                C[(size_t)row * N_ + col] = f2bf(fast_tanh(acc[ti][tj][reg] + bv));
            }
        }
    }
}

// ---------------------------------------------------------------------------
// R8 (resubmitted R9 — R3 bench was an infra failure, no kernel verdict):
// GEMM3 kernel — R6's verified 16x16 ring pipeline (0 bank conflicts), with
// the epilogue REPLACED: stage the 256x256 bf16 C tile in the (now dead)
// 128 KiB LDS ring, then read back linearly and emit 1KB-per-wave-instruction
// NON-TEMPORAL stores (full lines, no write-allocate). R6's direct 16x16
// stores were 32B half-lines: +123MB write amp + RMW fetch. R7 proved the
// 32x32 alternative re-introduces 1.3e7 bank conflicts and is net slower.
//   - C-stage swizzle: col' = col ^ (((row>>2)&3)<<4). Key == kg exactly, so
//     each 16-lane quarter writes a disjoint 16-col (8-bank) group ->
//     conflict-free ds_write_b16. Readback un-permutes 16B chunks within
//     each row (chunk j at j^(key<<1)) -> contiguous global stores.
//   - spline_post: nontemporal loads (net, v_in) + stores (v_out).
// ---------------------------------------------------------------------------
#define SLOT_U (256 * 32)   // ushorts per ring slot (16 KiB)

__device__ __forceinline__ void stage16(
    const ushort_t* __restrict__ gsrc, ushort_t* lds_dst)
{
    __builtin_amdgcn_global_load_lds(
        (const __attribute__((address_space(1))) void*)gsrc,
        (__attribute__((address_space(3))) void*)lds_dst, 16, 0, 0);
}

template <bool PERM_BIAS>
__global__ __launch_bounds__(512, 2) void gemm3_bt_tanh_256(
    const ushort_t* __restrict__ A,
    const ushort_t* __restrict__ BT,
    const float* __restrict__ bias,
    ushort_t* __restrict__ C,
    int N_, int K)
{
    // one contiguous 128 KiB block: ring [A 64K | B 64K] during the loop,
    // reused as the 256x256 bf16 C-stage after the loop.
    __shared__ __align__(16) ushort_t smem[8 * SLOT_U];
    ushort_t* sA = smem;
    ushort_t* sB = smem + 4 * SLOT_U;

    const int t    = threadIdx.x;
    const int lane = t & 63;
    const int w    = t >> 6;
    const int wy   = w >> 2;        // 0..1  (M)
    const int wx   = w & 3;         // 0..3  (N)
    const int l15  = lane & 15;
    const int kg   = lane >> 4;     // 0..3  k-group (8 bf16 each)

    // XCD-aware bijective swizzle (nwg % 8 == 0 in all tiers).
    const int gx  = gridDim.x;
    const int nwg = gx * gridDim.y;
    int id = blockIdx.y * gx + blockIdx.x;
    id = (id & 7) * (nwg >> 3) + (id >> 3);
    const int brow = (id / gx) * 256;
    const int bcol = (id % gx) * 256;

    f32x4 acc[8][4] = {};

    // staging: thread t -> row rL = t>>2, LDS chunk slot t&3 holding global
    // chunk g = (t&3) ^ ((rL>>1)&3).
    const int rL  = t >> 2;
    const int g8  = (((t & 3) ^ ((t >> 3) & 3)) << 3);   // elem offset of chunk
    const int wbU = (t & ~63) * 8;                       // wave-uniform base (ushorts)
    const size_t rowA0 = (size_t)(brow + rL) * K;
    const size_t rowA1 = (size_t)(brow + 128 + rL) * K;
    const size_t rowB0 = (size_t)(bcol + rL) * K;
    const size_t rowB1 = (size_t)(bcol + 128 + rL) * K;

    // fragment read offsets (ushort units within a slot), swizzled
    int offA[8], offB[4];
#pragma unroll
    for (int m = 0; m < 8; ++m) {
        const int r = wy * 128 + m * 16 + l15;
        offA[m] = r * 32 + (((kg ^ (r >> 1)) & 3) << 3);
    }
#pragma unroll
    for (int n = 0; n < 4; ++n) {
        const int r = wx * 64 + n * 16 + l15;
        offB[n] = r * 32 + (((kg ^ (r >> 1)) & 3) << 3);
    }

    const int NT = K >> 5;   // K-slices of 32 (K=1024 -> 32; NT >= 4 required)

    // prologue: stage slices 0,1,2 (12 issues); vmcnt(8) -> slice 0 landed.
#pragma unroll
    for (int sp = 0; sp < 3; ++sp) {
        const int kk = sp << 5;
        ushort_t* dA = sA + sp * SLOT_U + wbU;
        ushort_t* dB = sB + sp * SLOT_U + wbU;
        stage16(A  + rowA0 + kk + g8, dA);
        stage16(BT + rowB0 + kk + g8, dB);
        stage16(A  + rowA1 + kk + g8, dA + 4096);
        stage16(BT + rowB1 + kk + g8, dB + 4096);
    }
    asm volatile("s_waitcnt vmcnt(8)" ::: "memory");
    __builtin_amdgcn_s_barrier();

    for (int s = 0; s < NT; ++s) {
        const ushort_t* sAs = sA + (s & 3) * SLOT_U;
        const ushort_t* sBs = sB + (s & 3) * SLOT_U;
        const int sp = s + 3;
        const int kk = sp << 5;
        ushort_t* dA = sA + (sp & 3) * SLOT_U + wbU;
        ushort_t* dB = sB + (sp & 3) * SLOT_U + wbU;

        // ---- phase A: read B0-3 + A0-3 (8 b128); stage issue-0 pair ----
        bf16x8 bR[4], aR[4];
#pragma unroll
        for (int n = 0; n < 4; ++n) bR[n] = *(const bf16x8*)(sBs + offB[n]);
#pragma unroll
        for (int m = 0; m < 4; ++m) aR[m] = *(const bf16x8*)(sAs + offA[m]);
        if (sp < NT) {
            stage16(A  + rowA0 + kk + g8, dA);
            stage16(BT + rowB0 + kk + g8, dB);
        }
        __builtin_amdgcn_s_barrier();
        asm volatile("s_waitcnt lgkmcnt(0)");
        __builtin_amdgcn_s_setprio(1);
#pragma unroll
        for (int m = 0; m < 4; ++m)
#pragma unroll
            for (int n = 0; n < 4; ++n)
                acc[m][n] = __builtin_amdgcn_mfma_f32_16x16x32_bf16(
                    aR[m], bR[n], acc[m][n], 0, 0, 0);
        __builtin_amdgcn_s_setprio(0);
        __builtin_amdgcn_s_barrier();

        // ---- phase B: read A4-7 (4 b128); stage issue-1 pair ----
#pragma unroll
        for (int m = 0; m < 4; ++m) aR[m] = *(const bf16x8*)(sAs + offA[4 + m]);
        if (sp < NT) {
            stage16(A  + rowA1 + kk + g8, dA + 4096);
            stage16(BT + rowB1 + kk + g8, dB + 4096);
        }
        __builtin_amdgcn_s_barrier();
        asm volatile("s_waitcnt lgkmcnt(0)");
        __builtin_amdgcn_s_setprio(1);
#pragma unroll
        for (int m = 0; m < 4; ++m)
#pragma unroll
            for (int n = 0; n < 4; ++n)
                acc[4 + m][n] = __builtin_amdgcn_mfma_f32_16x16x32_bf16(
                    aR[m], bR[n], acc[4 + m][n], 0, 0, 0);
        __builtin_amdgcn_s_setprio(0);

        // ---- slice boundary: drain slice s+1 only, keep s+2/s+3 in flight ----
        if (s < NT - 3)       asm volatile("s_waitcnt vmcnt(8)" ::: "memory");
        else if (s == NT - 3) asm volatile("s_waitcnt vmcnt(4)" ::: "memory");
        else if (s == NT - 2) asm volatile("s_waitcnt vmcnt(0)" ::: "memory");
        __builtin_amdgcn_s_barrier();
    }

    // ---- epilogue: tanh+bias -> LDS C-stage (swizzled, conflict-free) ----
    // 16x16 C/D mapping: col=lane&15, row=(lane>>4)*4+reg [m89 verified].
    ushort_t* sC = smem;   // 256 x 256 bf16 = 128 KiB, exactly the ring
#pragma unroll
    for (int n = 0; n < 4; ++n) {
        const int cg  = wx * 64 + n * 16 + l15;
        const int col = bcol + cg;
        const int bidx = PERM_BIAS ? ((col & 511) * 17 + (col >> 9)) : col;
        const float bv = bias[bidx];
#pragma unroll
        for (int m = 0; m < 8; ++m) {
            const int rg0 = wy * 128 + m * 16 + kg * 4;       // 4-aligned
            const int cgs = cg ^ (((rg0 >> 2) & 3) << 4);     // quarter-disjoint
#pragma unroll
            for (int reg = 0; reg < 4; ++reg)
                sC[(rg0 + reg) * 256 + cgs] =
                    f2bf(fast_tanh(acc[m][n][reg] + bv));
        }
    }
    __syncthreads();

    // ---- readback: rows linear, 16B chunks un-permuted; nt 1KB stores ----
#pragma unroll
    for (int i = 0; i < 16; ++i) {
        const int slot = i * 512 + t;        // 8192 chunk-slots = 256 rows x 32
        const int r  = slot >> 5;
        const int j  = slot & 31;
        const int js = j ^ (((r >> 2) & 3) << 1);
        const i32x4 v = *(const i32x4*)(sC + r * 256 + js * 8);
        __builtin_nontemporal_store(
            v, (i32x4*)(C + (size_t)(brow + r) * N_ + bcol + j * 8));
    }
}

// ---------------------------------------------------------------------------
// Spline postprocess, plane-major net layout: net[b][p*512 + n] holds value
// p of unit n (p<9: h_net, p>=9: w_net). One block per batch row, 256
// threads; thread t handles units 2t, 2t+1 via dword plane loads (coalesced).
// R8: nontemporal loads/stores (all data read/written exactly once).
// ---------------------------------------------------------------------------
__global__ __launch_bounds__(256) void spline_post(
    const ushort_t* __restrict__ net,   // rows x OUTD bf16, plane-major
    const float* __restrict__ v_in,     // rows x 2N
    const float* __restrict__ ld_in,    // rows
    float* __restrict__ v_out,          // rows x 2N
    float* __restrict__ ld_out)         // rows
{
    const int b = blockIdx.x;
    const int t = threadIdx.x;          // 0..255

    unsigned int pl[17];
    const ushort_t* base = net + (size_t)b * OUTD + 2 * t;
#pragma unroll
    for (int p = 0; p < 17; ++p)
        pl[p] = __builtin_nontemporal_load((const unsigned int*)(base + p * 512));

    {
        const f32x2v vp = __builtin_nontemporal_load(
            (const f32x2v*)(v_in + (size_t)b * (2 * NN) + 2 * t));
        __builtin_nontemporal_store(
            vp, (f32x2v*)(v_out + (size_t)b * (2 * NN) + 2 * t));
    }
    const f32x2v va2 = __builtin_nontemporal_load(
        (const f32x2v*)(v_in + (size_t)b * (2 * NN) + NN + 2 * t));

    float vact[2];
    float lt_sum = 0.f;
#pragma unroll 1
    for (int u = 0; u < 2; ++u) {
        const int sh = u * 16;
        float t17[17];
#pragma unroll
        for (int p = 0; p < 17; ++p)
            t17[p] = bf2f((ushort_t)(pl[p] >> sh));

        float m = t17[9];
#pragma unroll
        for (int i = 10; i < 17; i++) m = fmaxf(m, t17[i]);
        float wn[8], wsum = 0.f;
#pragma unroll
        for (int i = 0; i < 8; i++) { wn[i] = __expf(t17[9 + i] - m); wsum += wn[i]; }
        const float winv = 1.f / wsum;
#pragma unroll
        for (int i = 0; i < 8; i++) wn[i] *= winv;

        float eh[9];
#pragma unroll
        for (int i = 0; i < 9; i++) eh[i] = __expf(t17[i]);
        float denom = 0.f;
#pragma unroll
        for (int k = 0; k < 8; k++) denom += 0.5f * wn[k] * (eh[k] + eh[k + 1]);
        const float dinv = 1.f / denom;
        float hn[9];
#pragma unroll
        for (int i = 0; i < 9; i++) hn[i] = eh[i] * dinv;

        float kx[9], ky[9];
        kx[0] = 0.f; ky[0] = 0.f;
#pragma unroll
        for (int k = 0; k < 8; k++) {
            kx[k + 1] = kx[k] + wn[k];
            ky[k + 1] = ky[k] + 0.5f * wn[k] * (hn[k] + hn[k + 1]);
        }

        const float va = (u == 0) ? va2.x : va2.y;
        int cnt = 0;
#pragma unroll
        for (int j = 0; j < 9; j++) cnt += (kx[j] < va) ? 1 : 0;
        int k = cnt - 1;
        k = k < 0 ? 0 : (k > KKN - 1 ? KKN - 1 : k);

        const float wseg = wn[k];
        const float hlo = hn[k], hhi = hn[k + 1];
        const float xlo = kx[k], ylo = ky[k];
        const float alpha = (va - xlo) / wseg;
        vact[u] = ylo + alpha * hlo * wseg + 0.5f * alpha * alpha * (hhi - hlo) * wseg;
        lt_sum += __logf(hlo + alpha * (hhi - hlo));
    }

    {
        f32x2v vo; vo.x = vact[0]; vo.y = vact[1];
        __builtin_nontemporal_store(
            vo, (f32x2v*)(v_out + (size_t)b * (2 * NN) + NN + 2 * t));
    }

    __shared__ float wred[4];
#pragma unroll
    for (int o = 32; o > 0; o >>= 1) lt_sum += __shfl_down(lt_sum, o, 64);
    if ((t & 63) == 0) wred[t >> 6] = lt_sum;
    __syncthreads();
    if (t == 0)
        ld_out[b] = ld_in[b] - (wred[0] + wred[1] + wred[2] + wred[3]);
}

// ---------------------------------------------------------------------------
extern "C" void kernel_launch(void* const* d_in, const int* in_sizes, int n_in,
                              void* d_out, int out_size, void* d_ws, size_t ws_size,
                              hipStream_t stream)
{
    const float* v_in = (const float*)d_in[0];   // B x 2N
    const float* ld   = (const float*)d_in[1];   // B x 1
    const float* W1   = (const float*)d_in[2];   // N x H
    const float* b1   = (const float*)d_in[3];   // H
    const float* W2   = (const float*)d_in[4];   // H x H
    const float* b2   = (const float*)d_in[5];   // H
    const float* W3   = (const float*)d_in[6];   // H x OUTD
    const float* b3   = (const float*)d_in[7];   // OUTD

    float* out    = (float*)d_out;
    float* v_out  = out;                           // B*2N
    float* ld_out = out + (size_t)BB * (2 * NN);   // B

    // Workspace tiers (R3-verified: full tier 172Mi fits):
    //   [0, region)       chunk net buffer (plane-major); a0b + x1b alias here
    //   [region, +16Mi)   x2b ; then W1T (1Mi) W2T (2Mi) W3T (17Mi)
    const size_t Mi = 1048576;
    int    chunk;
    size_t region;
    if      (ws_size >= 172 * Mi) { chunk = 8192; region = 136 * Mi; }
    else if (ws_size >= 104 * Mi) { chunk = 4096; region =  68 * Mi; }
    else if (ws_size >=  70 * Mi) { chunk = 2048; region =  34 * Mi; }
    else                          { chunk = 1024; region =  24 * Mi; }

    char* ws = (char*)d_ws;
    ushort_t* a0b = (ushort_t*)(ws);
    ushort_t* x1b = (ushort_t*)(ws + 8 * Mi);
    ushort_t* netc = (ushort_t*)(ws);                       // chunk buffer
    ushort_t* x2b = (ushort_t*)(ws + region);
    ushort_t* W1T = (ushort_t*)(ws + region + 16 * Mi);
    ushort_t* W2T = (ushort_t*)(ws + region + 17 * Mi);
    ushort_t* W3T = (ushort_t*)(ws + region + 19 * Mi);

    // conversions
    conv_v<<<dim3(BB * NN / 2 / 256), dim3(256), 0, stream>>>(v_in, a0b);
    transpose_cvt<false><<<dim3(HH / 32, NN / 32),   dim3(32, 8), 0, stream>>>(W1, W1T, NN, HH);
    transpose_cvt<false><<<dim3(HH / 32, HH / 32),   dim3(32, 8), 0, stream>>>(W2, W2T, HH, HH);
    transpose_cvt<true ><<<dim3(OUTD / 32, HH / 32), dim3(32, 8), 0, stream>>>(W3, W3T, HH, OUTD);

    // GEMM1: x1 = tanh((v_passive-0.5) @ W1 + b1)   M=8192 N=1024 K=512
    gemm_bt_tanh<false><<<dim3(HH / 128, BB / 128), dim3(256), 0, stream>>>(
        a0b, W1T, b1, x1b, HH, NN);
    // GEMM2: x2 = tanh(x1 @ W2 + b2)                M=8192 N=1024 K=1024
    gemm_bt_tanh<false><<<dim3(HH / 128, BB / 128), dim3(256), 0, stream>>>(
        x1b, W2T, b2, x2b, HH, HH);

    // GEMM3 + spline, chunked (single pass when chunk==8192)
    // R8/R9: R6 pipeline + LDS-staged nt-store epilogue.
    for (int c = 0; c < BB / chunk; ++c) {
        const ushort_t* xa = x2b + (size_t)c * chunk * HH;
        gemm3_bt_tanh_256<true><<<dim3(OUTD / 256, chunk / 256), dim3(512), 0, stream>>>(
            xa, W3T, b3, netc, OUTD, HH);
        spline_post<<<dim3(chunk), dim3(256), 0, stream>>>(
            netc,
            v_in   + (size_t)c * chunk * (2 * NN),
            ld     + (size_t)c * chunk,
            v_out  + (size_t)c * chunk * (2 * NN),
            ld_out + (size_t)c * chunk);
    }
}

// Round 5
// 393.033 us; speedup vs baseline: 1.0565x; 1.0007x over previous
//
#include <hip/hip_runtime.h>
#include <math.h>

// Problem constants
#define BB    8192
#define NN    512
#define KKN   8
#define HH    1024
#define OUTD  (NN * (2 * KKN + 1))   // 8704

typedef unsigned short ushort_t;
typedef __bf16 bf16x8 __attribute__((ext_vector_type(8)));
typedef float  f32x16 __attribute__((ext_vector_type(16)));
typedef float  f32x4  __attribute__((ext_vector_type(4)));
typedef int    i32x4  __attribute__((ext_vector_type(4)));
typedef float  f32x2v __attribute__((ext_vector_type(2)));

// float -> bf16 round-to-nearest-even
__device__ inline ushort_t f2bf(float f) {
    unsigned int u = __float_as_uint(f);
    unsigned int r = (u + 0x7fffu + ((u >> 16) & 1u)) >> 16;
    return (ushort_t)r;
}
__device__ inline float bf2f(ushort_t u) {
    return __uint_as_float(((unsigned int)u) << 16);
}

// 5-op tanh: 1 - 2/(e^{2x}+1). Saturates correctly for |x| large.
__device__ inline float fast_tanh(float x) {
    float t = __expf(x + x);
    return fmaf(-2.f, __builtin_amdgcn_rcpf(t + 1.f), 1.f);
}

// ---------------------------------------------------------------------------
// conv_v: a0b[b][n] = bf16(v_in[b][n] - 0.5), n in [0,512). v_in rows are 1024.
// ---------------------------------------------------------------------------
__global__ __launch_bounds__(256) void conv_v(
    const float* __restrict__ v_in, ushort_t* __restrict__ a0b)
{
    int t = blockIdx.x * 256 + threadIdx.x;          // 0 .. B*512/2-1
    int e0 = t * 2;
    int b = e0 >> 9;
    int n = e0 & 511;
    const float2 v = *(const float2*)(v_in + (size_t)b * (2 * NN) + n);
    ushort_t* o = a0b + (size_t)b * NN + n;
    o[0] = f2bf(v.x - 0.5f);
    o[1] = f2bf(v.y - 0.5f);
}

// ---------------------------------------------------------------------------
// transpose_cvt: W (Kd x Nd fp32 row-major) -> WT (Nd x Kd bf16 row-major)
// PERM: out-row r is remapped to (r%17)*512 + r/17 (plane-major net layout)
// ---------------------------------------------------------------------------
template <bool PERM>
__global__ __launch_bounds__(256) void transpose_cvt(
    const float* __restrict__ W, ushort_t* __restrict__ WT, int Kd, int Nd)
{
    __shared__ float tile[32][33];
    const int bx = blockIdx.x * 32;   // n base
    const int by = blockIdx.y * 32;   // k base
    const int tx = threadIdx.x;       // 0..31
    const int ty = threadIdx.y;       // 0..7
#pragma unroll
    for (int i = 0; i < 32; i += 8)
        tile[ty + i][tx] = W[(size_t)(by + ty + i) * Nd + bx + tx];
    __syncthreads();
#pragma unroll
    for (int i = 0; i < 32; i += 8) {
        int r = bx + ty + i;
        if (PERM) r = (r % 17) * 512 + (r / 17);
        WT[(size_t)r * Kd + by + tx] = f2bf(tile[tx][ty + i]);
    }
}

// ---------------------------------------------------------------------------
// bf16 MFMA GEMM, 32x32x16 shape: C = bf16(tanh(A @ B + bias))  (128x128 tile)
// Kept for GEMM1/GEMM2 (small-N shapes; B fully L2-resident there; proven).
// ---------------------------------------------------------------------------
template <bool PERM_BIAS>
__global__ __launch_bounds__(256) void gemm_bt_tanh(
    const ushort_t* __restrict__ A,
    const ushort_t* __restrict__ BT,
    const float* __restrict__ bias,
    ushort_t* __restrict__ C,
    int N_, int K)
{
    __shared__ __align__(16) ushort_t sA[128 * 32];   // [row][k-chunk swizzled] 8 KB
    __shared__ __align__(16) ushort_t sB[128 * 32];

    const int t    = threadIdx.x;
    const int lane = t & 63;
    const int w    = t >> 6;
    const int wy   = w >> 1;
    const int wx   = w & 1;
    const int l31  = lane & 31;
    const int h    = lane >> 5;       // k-half within fragment

    const int brow = blockIdx.y * 128;
    const int bcol = blockIdx.x * 128;

    f32x16 acc[2][2] = {};

    const int cwb = (t & ~63);       // wave-uniform chunk base

    int rS[2], gS[2];
#pragma unroll
    for (int p = 0; p < 2; ++p) {
        const int c = p * 256 + t;
        rS[p] = c >> 2;
        gS[p] = ((c & 3) - (rS[p] >> 1)) & 3;
    }

    int offA[2][2], offB[2][2];
#pragma unroll
    for (int ks = 0; ks < 2; ++ks)
#pragma unroll
        for (int ti = 0; ti < 2; ++ti) {
            const int rA = wy * 64 + ti * 32 + l31;
            offA[ks][ti] = rA * 32 + ((2 * ks + h + (rA >> 1)) & 3) * 8;
            const int rB = wx * 64 + ti * 32 + l31;
            offB[ks][ti] = rB * 32 + ((2 * ks + h + (rB >> 1)) & 3) * 8;
        }

    for (int k0 = 0; k0 < K; k0 += 32) {
        __syncthreads();
#pragma unroll
        for (int p = 0; p < 2; ++p) {
            const int cb = p * 256 + cwb;
            const ushort_t* ga = A  + (size_t)(brow + rS[p]) * K + k0 + gS[p] * 8;
            const ushort_t* gb = BT + (size_t)(bcol + rS[p]) * K + k0 + gS[p] * 8;
            __builtin_amdgcn_global_load_lds(
                (const __attribute__((address_space(1))) void*)ga,
                (__attribute__((address_space(3))) void*)(sA + (size_t)cb * 8), 16, 0, 0);
            __builtin_amdgcn_global_load_lds(
                (const __attribute__((address_space(1))) void*)gb,
                (__attribute__((address_space(3))) void*)(sB + (size_t)cb * 8), 16, 0, 0);
        }
        __syncthreads();

#pragma unroll
        for (int ks = 0; ks < 2; ++ks) {
            const bf16x8 a0 = *(const bf16x8*)(sA + offA[ks][0]);
            const bf16x8 a1 = *(const bf16x8*)(sA + offA[ks][1]);
            const bf16x8 b0 = *(const bf16x8*)(sB + offB[ks][0]);
            const bf16x8 b1 = *(const bf16x8*)(sB + offB[ks][1]);
            acc[0][0] = __builtin_amdgcn_mfma_f32_32x32x16_bf16(a0, b0, acc[0][0], 0, 0, 0);
            acc[0][1] = __builtin_amdgcn_mfma_f32_32x32x16_bf16(a0, b1, acc[0][1], 0, 0, 0);
            acc[1][0] = __builtin_amdgcn_mfma_f32_32x32x16_bf16(a1, b0, acc[1][0], 0, 0, 0);
            acc[1][1] = __builtin_amdgcn_mfma_f32_32x32x16_bf16(a1, b1, acc[1][1], 0, 0, 0);
        }
    }

#pragma unroll
    for (int tj = 0; tj < 2; ++tj) {
        const int col = bcol + wx * 64 + tj * 32 + l31;
        const int bidx = PERM_BIAS ? ((col & 511) * 17 + (col >> 9)) : col;
        const float bv = bias[bidx];
#pragma unroll
        for (int ti = 0; ti < 2; ++ti) {
            const int rb = brow + wy * 64 + ti * 32 + 4 * h;
#pragma unroll
            for (int reg = 0; reg < 16; ++reg) {
                const int row = rb + (reg & 3) + 8 * (reg >> 2);
                C[(size_t)row * N_ + col] = f2bf(fast_tanh(acc[ti][tj][reg] + bv));
            }
        }
    }
}

// ---------------------------------------------------------------------------
// R10: GEMM3 kernel — R8's verified pipeline + LDS-staged nt epilogue,
// with ONE change: L2-aware 2D within-XCD block ordering.
//   R8 counters: FETCH 295.7MB (vs 34.6MB unique inputs) = B-panel re-fetch.
//   Old order: XCD k swept its 4 tile-rows ROW-major -> 32 concurrent blocks
//   = 1 row = 32 distinct B-panels (16MB) thrashing the 4MB per-XCD L2.
//   New order: sweep in col-groups of 8 -> concurrent set = 4 rows x 8 cols
//   = 4 A-panels (2MB, resident) + 8 B-panels (4MB, refilled once/group).
//   Per-XCD L2 fill 73MB -> 19MB; all XCDs walk the same col-group schedule
//   so L3 serves B cross-XCD.
// ---------------------------------------------------------------------------
#define SLOT_U (256 * 32)   // ushorts per ring slot (16 KiB)

__device__ __forceinline__ void stage16(
    const ushort_t* __restrict__ gsrc, ushort_t* lds_dst)
{
    __builtin_amdgcn_global_load_lds(
        (const __attribute__((address_space(1))) void*)gsrc,
        (__attribute__((address_space(3))) void*)lds_dst, 16, 0, 0);
}

template <bool PERM_BIAS>
__global__ __launch_bounds__(512, 2) void gemm3_bt_tanh_256(
    const ushort_t* __restrict__ A,
    const ushort_t* __restrict__ BT,
    const float* __restrict__ bias,
    ushort_t* __restrict__ C,
    int N_, int K)
{
    // one contiguous 128 KiB block: ring [A 64K | B 64K] during the loop,
    // reused as the 256x256 bf16 C-stage after the loop.
    __shared__ __align__(16) ushort_t smem[8 * SLOT_U];
    ushort_t* sA = smem;
    ushort_t* sB = smem + 4 * SLOT_U;

    const int t    = threadIdx.x;
    const int lane = t & 63;
    const int w    = t >> 6;
    const int wy   = w >> 2;        // 0..1  (M)
    const int wx   = w & 3;         // 0..3  (N)
    const int l15  = lane & 15;
    const int kg   = lane >> 4;     // 0..3  k-group (8 bf16 each)

    // R10: XCD binding (xcd = orig id % 8) + 2D within-XCD order.
    // XCD k owns tile-rows [k*rpx, (k+1)*rpx); within, col-groups of 8
    // swept row-minor: seq -> (g, rem) -> col = g*8 + rem%gw, row = rem/gw.
    const int gx = gridDim.x, gy = gridDim.y;
    int br, bc;
    {
        const int o = blockIdx.y * gx + blockIdx.x;
        if ((gy & 7) == 0) {
            const int rpx = gy >> 3;          // tile-rows per XCD
            const int xcd = o & 7;
            const int seq = o >> 3;           // 0 .. rpx*gx-1
            const int bpg = rpx << 3;         // blocks per col-group (G=8)
            const int g   = seq / bpg;
            const int rem = seq % bpg;
            const int gcw = gx - g * 8;
            const int gw  = gcw < 8 ? gcw : 8;
            bc = g * 8 + rem % gw;
            br = xcd * rpx + rem / gw;
        } else {                               // fallback: old bijective remap
            const int nwg = gx * gy;
            const int id = (o & 7) * (nwg >> 3) + (o >> 3);
            br = id / gx; bc = id % gx;
        }
    }
    const int brow = br * 256;
    const int bcol = bc * 256;

    f32x4 acc[8][4] = {};

    // staging: thread t -> row rL = t>>2, LDS chunk slot t&3 holding global
    // chunk g = (t&3) ^ ((rL>>1)&3).
    const int rL  = t >> 2;
    const int g8  = (((t & 3) ^ ((t >> 3) & 3)) << 3);   // elem offset of chunk
    const int wbU = (t & ~63) * 8;                       // wave-uniform base (ushorts)
    const size_t rowA0 = (size_t)(brow + rL) * K;
    const size_t rowA1 = (size_t)(brow + 128 + rL) * K;
    const size_t rowB0 = (size_t)(bcol + rL) * K;
    const size_t rowB1 = (size_t)(bcol + 128 + rL) * K;

    // fragment read offsets (ushort units within a slot), swizzled
    int offA[8], offB[4];
#pragma unroll
    for (int m = 0; m < 8; ++m) {
        const int r = wy * 128 + m * 16 + l15;
        offA[m] = r * 32 + (((kg ^ (r >> 1)) & 3) << 3);
    }
#pragma unroll
    for (int n = 0; n < 4; ++n) {
        const int r = wx * 64 + n * 16 + l15;
        offB[n] = r * 32 + (((kg ^ (r >> 1)) & 3) << 3);
    }

    const int NT = K >> 5;   // K-slices of 32 (K=1024 -> 32; NT >= 4 required)

    // prologue: stage slices 0,1,2 (12 issues); vmcnt(8) -> slice 0 landed.
#pragma unroll
    for (int sp = 0; sp < 3; ++sp) {
        const int kk = sp << 5;
        ushort_t* dA = sA + sp * SLOT_U + wbU;
        ushort_t* dB = sB + sp * SLOT_U + wbU;
        stage16(A  + rowA0 + kk + g8, dA);
        stage16(BT + rowB0 + kk + g8, dB);
        stage16(A  + rowA1 + kk + g8, dA + 4096);
        stage16(BT + rowB1 + kk + g8, dB + 4096);
    }
    asm volatile("s_waitcnt vmcnt(8)" ::: "memory");
    __builtin_amdgcn_s_barrier();

    for (int s = 0; s < NT; ++s) {
        const ushort_t* sAs = sA + (s & 3) * SLOT_U;
        const ushort_t* sBs = sB + (s & 3) * SLOT_U;
        const int sp = s + 3;
        const int kk = sp << 5;
        ushort_t* dA = sA + (sp & 3) * SLOT_U + wbU;
        ushort_t* dB = sB + (sp & 3) * SLOT_U + wbU;

        // ---- phase A: read B0-3 + A0-3 (8 b128); stage issue-0 pair ----
        bf16x8 bR[4], aR[4];
#pragma unroll
        for (int n = 0; n < 4; ++n) bR[n] = *(const bf16x8*)(sBs + offB[n]);
#pragma unroll
        for (int m = 0; m < 4; ++m) aR[m] = *(const bf16x8*)(sAs + offA[m]);
        if (sp < NT) {
            stage16(A  + rowA0 + kk + g8, dA);
            stage16(BT + rowB0 + kk + g8, dB);
        }
        __builtin_amdgcn_s_barrier();
        asm volatile("s_waitcnt lgkmcnt(0)");
        __builtin_amdgcn_s_setprio(1);
#pragma unroll
        for (int m = 0; m < 4; ++m)
#pragma unroll
            for (int n = 0; n < 4; ++n)
                acc[m][n] = __builtin_amdgcn_mfma_f32_16x16x32_bf16(
                    aR[m], bR[n], acc[m][n], 0, 0, 0);
        __builtin_amdgcn_s_setprio(0);
        __builtin_amdgcn_s_barrier();

        // ---- phase B: read A4-7 (4 b128); stage issue-1 pair ----
#pragma unroll
        for (int m = 0; m < 4; ++m) aR[m] = *(const bf16x8*)(sAs + offA[4 + m]);
        if (sp < NT) {
            stage16(A  + rowA1 + kk + g8, dA + 4096);
            stage16(BT + rowB1 + kk + g8, dB + 4096);
        }
        __builtin_amdgcn_s_barrier();
        asm volatile("s_waitcnt lgkmcnt(0)");
        __builtin_amdgcn_s_setprio(1);
#pragma unroll
        for (int m = 0; m < 4; ++m)
#pragma unroll
            for (int n = 0; n < 4; ++n)
                acc[4 + m][n] = __builtin_amdgcn_mfma_f32_16x16x32_bf16(
                    aR[m], bR[n], acc[4 + m][n], 0, 0, 0);
        __builtin_amdgcn_s_setprio(0);

        // ---- slice boundary: drain slice s+1 only, keep s+2/s+3 in flight ----
        if (s < NT - 3)       asm volatile("s_waitcnt vmcnt(8)" ::: "memory");
        else if (s == NT - 3) asm volatile("s_waitcnt vmcnt(4)" ::: "memory");
        else if (s == NT - 2) asm volatile("s_waitcnt vmcnt(0)" ::: "memory");
        __builtin_amdgcn_s_barrier();
    }

    // ---- epilogue: tanh+bias -> LDS C-stage (swizzled, conflict-free) ----
    // 16x16 C/D mapping: col=lane&15, row=(lane>>4)*4+reg [m89 verified].
    ushort_t* sC = smem;   // 256 x 256 bf16 = 128 KiB, exactly the ring
#pragma unroll
    for (int n = 0; n < 4; ++n) {
        const int cg  = wx * 64 + n * 16 + l15;
        const int col = bcol + cg;
        const int bidx = PERM_BIAS ? ((col & 511) * 17 + (col >> 9)) : col;
        const float bv = bias[bidx];
#pragma unroll
        for (int m = 0; m < 8; ++m) {
            const int rg0 = wy * 128 + m * 16 + kg * 4;       // 4-aligned
            const int cgs = cg ^ (((rg0 >> 2) & 3) << 4);     // quarter-disjoint
#pragma unroll
            for (int reg = 0; reg < 4; ++reg)
                sC[(rg0 + reg) * 256 + cgs] =
                    f2bf(fast_tanh(acc[m][n][reg] + bv));
        }
    }
    __syncthreads();

    // ---- readback: rows linear, 16B chunks un-permuted; nt 1KB stores ----
#pragma unroll
    for (int i = 0; i < 16; ++i) {
        const int slot = i * 512 + t;        // 8192 chunk-slots = 256 rows x 32
        const int r  = slot >> 5;
        const int j  = slot & 31;
        const int js = j ^ (((r >> 2) & 3) << 1);
        const i32x4 v = *(const i32x4*)(sC + r * 256 + js * 8);
        __builtin_nontemporal_store(
            v, (i32x4*)(C + (size_t)(brow + r) * N_ + bcol + j * 8));
    }
}

// ---------------------------------------------------------------------------
// Spline postprocess, plane-major net layout: net[b][p*512 + n] holds value
// p of unit n (p<9: h_net, p>=9: w_net). One block per batch row, 256
// threads; thread t handles units 2t, 2t+1 via dword plane loads (coalesced).
// nontemporal loads/stores (all data read/written exactly once).
// ---------------------------------------------------------------------------
__global__ __launch_bounds__(256) void spline_post(
    const ushort_t* __restrict__ net,   // rows x OUTD bf16, plane-major
    const float* __restrict__ v_in,     // rows x 2N
    const float* __restrict__ ld_in,    // rows
    float* __restrict__ v_out,          // rows x 2N
    float* __restrict__ ld_out)         // rows
{
    const int b = blockIdx.x;
    const int t = threadIdx.x;          // 0..255

    unsigned int pl[17];
    const ushort_t* base = net + (size_t)b * OUTD + 2 * t;
#pragma unroll
    for (int p = 0; p < 17; ++p)
        pl[p] = __builtin_nontemporal_load((const unsigned int*)(base + p * 512));

    {
        const f32x2v vp = __builtin_nontemporal_load(
            (const f32x2v*)(v_in + (size_t)b * (2 * NN) + 2 * t));
        __builtin_nontemporal_store(
            vp, (f32x2v*)(v_out + (size_t)b * (2 * NN) + 2 * t));
    }
    const f32x2v va2 = __builtin_nontemporal_load(
        (const f32x2v*)(v_in + (size_t)b * (2 * NN) + NN + 2 * t));

    float vact[2];
    float lt_sum = 0.f;
#pragma unroll 1
    for (int u = 0; u < 2; ++u) {
        const int sh = u * 16;
        float t17[17];
#pragma unroll
        for (int p = 0; p < 17; ++p)
            t17[p] = bf2f((ushort_t)(pl[p] >> sh));

        float m = t17[9];
#pragma unroll
        for (int i = 10; i < 17; i++) m = fmaxf(m, t17[i]);
        float wn[8], wsum = 0.f;
#pragma unroll
        for (int i = 0; i < 8; i++) { wn[i] = __expf(t17[9 + i] - m); wsum += wn[i]; }
        const float winv = 1.f / wsum;
#pragma unroll
        for (int i = 0; i < 8; i++) wn[i] *= winv;

        float eh[9];
#pragma unroll
        for (int i = 0; i < 9; i++) eh[i] = __expf(t17[i]);
        float denom = 0.f;
#pragma unroll
        for (int k = 0; k < 8; k++) denom += 0.5f * wn[k] * (eh[k] + eh[k + 1]);
        const float dinv = 1.f / denom;
        float hn[9];
#pragma unroll
        for (int i = 0; i < 9; i++) hn[i] = eh[i] * dinv;

        float kx[9], ky[9];
        kx[0] = 0.f; ky[0] = 0.f;
#pragma unroll
        for (int k = 0; k < 8; k++) {
            kx[k + 1] = kx[k] + wn[k];
            ky[k + 1] = ky[k] + 0.5f * wn[k] * (hn[k] + hn[k + 1]);
        }

        const float va = (u == 0) ? va2.x : va2.y;
        int cnt = 0;
#pragma unroll
        for (int j = 0; j < 9; j++) cnt += (kx[j] < va) ? 1 : 0;
        int k = cnt - 1;
        k = k < 0 ? 0 : (k > KKN - 1 ? KKN - 1 : k);

        const float wseg = wn[k];
        const float hlo = hn[k], hhi = hn[k + 1];
        const float xlo = kx[k], ylo = ky[k];
        const float alpha = (va - xlo) / wseg;
        vact[u] = ylo + alpha * hlo * wseg + 0.5f * alpha * alpha * (hhi - hlo) * wseg;
        lt_sum += __logf(hlo + alpha * (hhi - hlo));
    }

    {
        f32x2v vo; vo.x = vact[0]; vo.y = vact[1];
        __builtin_nontemporal_store(
            vo, (f32x2v*)(v_out + (size_t)b * (2 * NN) + NN + 2 * t));
    }

    __shared__ float wred[4];
#pragma unroll
    for (int o = 32; o > 0; o >>= 1) lt_sum += __shfl_down(lt_sum, o, 64);
    if ((t & 63) == 0) wred[t >> 6] = lt_sum;
    __syncthreads();
    if (t == 0)
        ld_out[b] = ld_in[b] - (wred[0] + wred[1] + wred[2] + wred[3]);
}

// ---------------------------------------------------------------------------
extern "C" void kernel_launch(void* const* d_in, const int* in_sizes, int n_in,
                              void* d_out, int out_size, void* d_ws, size_t ws_size,
                              hipStream_t stream)
{
    const float* v_in = (const float*)d_in[0];   // B x 2N
    const float* ld   = (const float*)d_in[1];   // B x 1
    const float* W1   = (const float*)d_in[2];   // N x H
    const float* b1   = (const float*)d_in[3];   // H
    const float* W2   = (const float*)d_in[4];   // H x H
    const float* b2   = (const float*)d_in[5];   // H
    const float* W3   = (const float*)d_in[6];   // H x OUTD
    const float* b3   = (const float*)d_in[7];   // OUTD

    float* out    = (float*)d_out;
    float* v_out  = out;                           // B*2N
    float* ld_out = out + (size_t)BB * (2 * NN);   // B

    // Workspace tiers (R3-verified: full tier 172Mi fits):
    //   [0, region)       chunk net buffer (plane-major); a0b + x1b alias here
    //   [region, +16Mi)   x2b ; then W1T (1Mi) W2T (2Mi) W3T (17Mi)
    const size_t Mi = 1048576;
    int    chunk;
    size_t region;
    if      (ws_size >= 172 * Mi) { chunk = 8192; region = 136 * Mi; }
    else if (ws_size >= 104 * Mi) { chunk = 4096; region =  68 * Mi; }
    else if (ws_size >=  70 * Mi) { chunk = 2048; region =  34 * Mi; }
    else                          { chunk = 1024; region =  24 * Mi; }

    char* ws = (char*)d_ws;
    ushort_t* a0b = (ushort_t*)(ws);
    ushort_t* x1b = (ushort_t*)(ws + 8 * Mi);
    ushort_t* netc = (ushort_t*)(ws);                       // chunk buffer
    ushort_t* x2b = (ushort_t*)(ws + region);
    ushort_t* W1T = (ushort_t*)(ws + region + 16 * Mi);
    ushort_t* W2T = (ushort_t*)(ws + region + 17 * Mi);
    ushort_t* W3T = (ushort_t*)(ws + region + 19 * Mi);

    // conversions
    conv_v<<<dim3(BB * NN / 2 / 256), dim3(256), 0, stream>>>(v_in, a0b);
    transpose_cvt<false><<<dim3(HH / 32, NN / 32),   dim3(32, 8), 0, stream>>>(W1, W1T, NN, HH);
    transpose_cvt<false><<<dim3(HH / 32, HH / 32),   dim3(32, 8), 0, stream>>>(W2, W2T, HH, HH);
    transpose_cvt<true ><<<dim3(OUTD / 32, HH / 32), dim3(32, 8), 0, stream>>>(W3, W3T, HH, OUTD);

    // GEMM1: x1 = tanh((v_passive-0.5) @ W1 + b1)   M=8192 N=1024 K=512
    gemm_bt_tanh<false><<<dim3(HH / 128, BB / 128), dim3(256), 0, stream>>>(
        a0b, W1T, b1, x1b, HH, NN);
    // GEMM2: x2 = tanh(x1 @ W2 + b2)                M=8192 N=1024 K=1024
    gemm_bt_tanh<false><<<dim3(HH / 128, BB / 128), dim3(256), 0, stream>>>(
        x1b, W2T, b2, x2b, HH, HH);

    // GEMM3 + spline, chunked (single pass when chunk==8192)
    // R10: R8 pipeline + L2-aware 2D within-XCD block ordering.
    for (int c = 0; c < BB / chunk; ++c) {
        const ushort_t* xa = x2b + (size_t)c * chunk * HH;
        gemm3_bt_tanh_256<true><<<dim3(OUTD / 256, chunk / 256), dim3(512), 0, stream>>>(
            xa, W3T, b3, netc, OUTD, HH);
        spline_post<<<dim3(chunk), dim3(256), 0, stream>>>(
            netc,
            v_in   + (size_t)c * chunk * (2 * NN),
            ld     + (size_t)c * chunk,
            v_out  + (size_t)c * chunk * (2 * NN),
            ld_out + (size_t)c * chunk);
    }
}

// Round 6
// 380.114 us; speedup vs baseline: 1.0924x; 1.0340x over previous
//
#include <hip/hip_runtime.h>
#include <math.h>

// Problem constants
#define BB    8192
#define NN    512
#define KKN   8
#define HH    1024
#define OUTD  (NN * (2 * KKN + 1))   // 8704

typedef unsigned short ushort_t;
typedef __bf16 bf16x8 __attribute__((ext_vector_type(8)));
typedef float  f32x16 __attribute__((ext_vector_type(16)));
typedef float  f32x4  __attribute__((ext_vector_type(4)));
typedef int    i32x4  __attribute__((ext_vector_type(4)));
typedef float  f32x2v __attribute__((ext_vector_type(2)));

// float -> bf16 round-to-nearest-even
__device__ inline ushort_t f2bf(float f) {
    unsigned int u = __float_as_uint(f);
    unsigned int r = (u + 0x7fffu + ((u >> 16) & 1u)) >> 16;
    return (ushort_t)r;
}
__device__ inline float bf2f(ushort_t u) {
    return __uint_as_float(((unsigned int)u) << 16);
}

// 5-op tanh: 1 - 2/(e^{2x}+1). Saturates correctly for |x| large.
__device__ inline float fast_tanh(float x) {
    float t = __expf(x + x);
    return fmaf(-2.f, __builtin_amdgcn_rcpf(t + 1.f), 1.f);
}

// ---------------------------------------------------------------------------
// conv_v: a0b[b][n] = bf16(v_in[b][n] - 0.5), n in [0,512). v_in rows are 1024.
// ---------------------------------------------------------------------------
__global__ __launch_bounds__(256) void conv_v(
    const float* __restrict__ v_in, ushort_t* __restrict__ a0b)
{
    int t = blockIdx.x * 256 + threadIdx.x;          // 0 .. B*512/2-1
    int e0 = t * 2;
    int b = e0 >> 9;
    int n = e0 & 511;
    const float2 v = *(const float2*)(v_in + (size_t)b * (2 * NN) + n);
    ushort_t* o = a0b + (size_t)b * NN + n;
    o[0] = f2bf(v.x - 0.5f);
    o[1] = f2bf(v.y - 0.5f);
}

// ---------------------------------------------------------------------------
// transpose_cvt: W (Kd x Nd fp32 row-major) -> WT (Nd x Kd bf16 row-major)
// PERM: out-row r is remapped to (r%17)*512 + r/17 (plane-major net layout)
// ---------------------------------------------------------------------------
template <bool PERM>
__global__ __launch_bounds__(256) void transpose_cvt(
    const float* __restrict__ W, ushort_t* __restrict__ WT, int Kd, int Nd)
{
    __shared__ float tile[32][33];
    const int bx = blockIdx.x * 32;   // n base
    const int by = blockIdx.y * 32;   // k base
    const int tx = threadIdx.x;       // 0..31
    const int ty = threadIdx.y;       // 0..7
#pragma unroll
    for (int i = 0; i < 32; i += 8)
        tile[ty + i][tx] = W[(size_t)(by + ty + i) * Nd + bx + tx];
    __syncthreads();
#pragma unroll
    for (int i = 0; i < 32; i += 8) {
        int r = bx + ty + i;
        if (PERM) r = (r % 17) * 512 + (r / 17);
        WT[(size_t)r * Kd + by + tx] = f2bf(tile[tx][ty + i]);
    }
}

// ---------------------------------------------------------------------------
// bf16 MFMA GEMM, 32x32x16 shape: C = bf16(tanh(A @ B + bias))  (128x128 tile)
// Kept for GEMM1/GEMM2 (small-N shapes; B fully L2-resident there; proven).
// ---------------------------------------------------------------------------
template <bool PERM_BIAS>
__global__ __launch_bounds__(256) void gemm_bt_tanh(
    const ushort_t* __restrict__ A,
    const ushort_t* __restrict__ BT,
    const float* __restrict__ bias,
    ushort_t* __restrict__ C,
    int N_, int K)
{
    __shared__ __align__(16) ushort_t sA[128 * 32];   // [row][k-chunk swizzled] 8 KB
    __shared__ __align__(16) ushort_t sB[128 * 32];

    const int t    = threadIdx.x;
    const int lane = t & 63;
    const int w    = t >> 6;
    const int wy   = w >> 1;
    const int wx   = w & 1;
    const int l31  = lane & 31;
    const int h    = lane >> 5;       // k-half within fragment

    const int brow = blockIdx.y * 128;
    const int bcol = blockIdx.x * 128;

    f32x16 acc[2][2] = {};

    const int cwb = (t & ~63);       // wave-uniform chunk base

    int rS[2], gS[2];
#pragma unroll
    for (int p = 0; p < 2; ++p) {
        const int c = p * 256 + t;
        rS[p] = c >> 2;
        gS[p] = ((c & 3) - (rS[p] >> 1)) & 3;
    }

    int offA[2][2], offB[2][2];
#pragma unroll
    for (int ks = 0; ks < 2; ++ks)
#pragma unroll
        for (int ti = 0; ti < 2; ++ti) {
            const int rA = wy * 64 + ti * 32 + l31;
            offA[ks][ti] = rA * 32 + ((2 * ks + h + (rA >> 1)) & 3) * 8;
            const int rB = wx * 64 + ti * 32 + l31;
            offB[ks][ti] = rB * 32 + ((2 * ks + h + (rB >> 1)) & 3) * 8;
        }

    for (int k0 = 0; k0 < K; k0 += 32) {
        __syncthreads();
#pragma unroll
        for (int p = 0; p < 2; ++p) {
            const int cb = p * 256 + cwb;
            const ushort_t* ga = A  + (size_t)(brow + rS[p]) * K + k0 + gS[p] * 8;
            const ushort_t* gb = BT + (size_t)(bcol + rS[p]) * K + k0 + gS[p] * 8;
            __builtin_amdgcn_global_load_lds(
                (const __attribute__((address_space(1))) void*)ga,
                (__attribute__((address_space(3))) void*)(sA + (size_t)cb * 8), 16, 0, 0);
            __builtin_amdgcn_global_load_lds(
                (const __attribute__((address_space(1))) void*)gb,
                (__attribute__((address_space(3))) void*)(sB + (size_t)cb * 8), 16, 0, 0);
        }
        __syncthreads();

#pragma unroll
        for (int ks = 0; ks < 2; ++ks) {
            const bf16x8 a0 = *(const bf16x8*)(sA + offA[ks][0]);
            const bf16x8 a1 = *(const bf16x8*)(sA + offA[ks][1]);
            const bf16x8 b0 = *(const bf16x8*)(sB + offB[ks][0]);
            const bf16x8 b1 = *(const bf16x8*)(sB + offB[ks][1]);
            acc[0][0] = __builtin_amdgcn_mfma_f32_32x32x16_bf16(a0, b0, acc[0][0], 0, 0, 0);
            acc[0][1] = __builtin_amdgcn_mfma_f32_32x32x16_bf16(a0, b1, acc[0][1], 0, 0, 0);
            acc[1][0] = __builtin_amdgcn_mfma_f32_32x32x16_bf16(a1, b0, acc[1][0], 0, 0, 0);
            acc[1][1] = __builtin_amdgcn_mfma_f32_32x32x16_bf16(a1, b1, acc[1][1], 0, 0, 0);
        }
    }

#pragma unroll
    for (int tj = 0; tj < 2; ++tj) {
        const int col = bcol + wx * 64 + tj * 32 + l31;
        const int bidx = PERM_BIAS ? ((col & 511) * 17 + (col >> 9)) : col;
        const float bv = bias[bidx];
#pragma unroll
        for (int ti = 0; ti < 2; ++ti) {
            const int rb = brow + wy * 64 + ti * 32 + 4 * h;
#pragma unroll
            for (int reg = 0; reg < 16; ++reg) {
                const int row = rb + (reg & 3) + 8 * (reg >> 2);
                C[(size_t)row * N_ + col] = f2bf(fast_tanh(acc[ti][tj][reg] + bv));
            }
        }
    }
}

// ---------------------------------------------------------------------------
// R11: GEMM3 kernel — R10's pipeline with the SCHEDULE de-serialized.
//   R10 counters: FETCH fixed (108MB), WRITE ideal (139MB), conflicts 0,
//   HBM 15%, MfmaUtil 31%. Per-slice budget: LDS traffic ~1.5k cyc, MFMA
//   ~1.2k cyc, measured slice ~3.1k cyc -> the 4 barriers/slice + blanket
//   lgkmcnt(0) lockstep the waves so LDS and MFMA pipes alternate instead of
//   pipelining.
//   Change: ONE barrier per slice (boundary vmcnt+barrier). Mid barriers and
//   asm lgkmcnt(0) removed — audit: (a) reads of slice s covered by vmcnt(8)
//   + boundary barrier of s-1 (per-wave vmcnt joined by barrier); (b) staging
//   into slot (s+3)&3 is safe because every wave's slice s-1 reads complete
//   before its consuming MFMAs (compiler data-dep lgkm waits) which precede
//   its boundary-barrier arrival. Compiler emits fine-grained lgkmcnt(4/3/1/0)
//   (m97 asm evidence) — first MFMA starts after 4 reads instead of all 12.
//   Waves now skew within a slice: LDS reads of one wave overlap MFMA of
//   another; setprio(1) arbitrates toward the MFMA-issuing waves.
// ---------------------------------------------------------------------------
#define SLOT_U (256 * 32)   // ushorts per ring slot (16 KiB)

__device__ __forceinline__ void stage16(
    const ushort_t* __restrict__ gsrc, ushort_t* lds_dst)
{
    __builtin_amdgcn_global_load_lds(
        (const __attribute__((address_space(1))) void*)gsrc,
        (__attribute__((address_space(3))) void*)lds_dst, 16, 0, 0);
}

template <bool PERM_BIAS>
__global__ __launch_bounds__(512, 2) void gemm3_bt_tanh_256(
    const ushort_t* __restrict__ A,
    const ushort_t* __restrict__ BT,
    const float* __restrict__ bias,
    ushort_t* __restrict__ C,
    int N_, int K)
{
    // one contiguous 128 KiB block: ring [A 64K | B 64K] during the loop,
    // reused as the 256x256 bf16 C-stage after the loop.
    __shared__ __align__(16) ushort_t smem[8 * SLOT_U];
    ushort_t* sA = smem;
    ushort_t* sB = smem + 4 * SLOT_U;

    const int t    = threadIdx.x;
    const int lane = t & 63;
    const int w    = t >> 6;
    const int wy   = w >> 2;        // 0..1  (M)
    const int wx   = w & 3;         // 0..3  (N)
    const int l15  = lane & 15;
    const int kg   = lane >> 4;     // 0..3  k-group (8 bf16 each)

    // R10: XCD binding (xcd = orig id % 8) + 2D within-XCD order.
    const int gx = gridDim.x, gy = gridDim.y;
    int br, bc;
    {
        const int o = blockIdx.y * gx + blockIdx.x;
        if ((gy & 7) == 0) {
            const int rpx = gy >> 3;          // tile-rows per XCD
            const int xcd = o & 7;
            const int seq = o >> 3;           // 0 .. rpx*gx-1
            const int bpg = rpx << 3;         // blocks per col-group (G=8)
            const int g   = seq / bpg;
            const int rem = seq % bpg;
            const int gcw = gx - g * 8;
            const int gw  = gcw < 8 ? gcw : 8;
            bc = g * 8 + rem % gw;
            br = xcd * rpx + rem / gw;
        } else {                               // fallback: old bijective remap
            const int nwg = gx * gy;
            const int id = (o & 7) * (nwg >> 3) + (o >> 3);
            br = id / gx; bc = id % gx;
        }
    }
    const int brow = br * 256;
    const int bcol = bc * 256;

    f32x4 acc[8][4] = {};

    // staging: thread t -> row rL = t>>2, LDS chunk slot t&3 holding global
    // chunk g = (t&3) ^ ((rL>>1)&3).
    const int rL  = t >> 2;
    const int g8  = (((t & 3) ^ ((t >> 3) & 3)) << 3);   // elem offset of chunk
    const int wbU = (t & ~63) * 8;                       // wave-uniform base (ushorts)
    const size_t rowA0 = (size_t)(brow + rL) * K;
    const size_t rowA1 = (size_t)(brow + 128 + rL) * K;
    const size_t rowB0 = (size_t)(bcol + rL) * K;
    const size_t rowB1 = (size_t)(bcol + 128 + rL) * K;

    // fragment read offsets (ushort units within a slot), swizzled
    int offA[8], offB[4];
#pragma unroll
    for (int m = 0; m < 8; ++m) {
        const int r = wy * 128 + m * 16 + l15;
        offA[m] = r * 32 + (((kg ^ (r >> 1)) & 3) << 3);
    }
#pragma unroll
    for (int n = 0; n < 4; ++n) {
        const int r = wx * 64 + n * 16 + l15;
        offB[n] = r * 32 + (((kg ^ (r >> 1)) & 3) << 3);
    }

    const int NT = K >> 5;   // K-slices of 32 (K=1024 -> 32; NT >= 4 required)

    // prologue: stage slices 0,1,2 (12 issues); vmcnt(8) -> slice 0 landed.
#pragma unroll
    for (int sp = 0; sp < 3; ++sp) {
        const int kk = sp << 5;
        ushort_t* dA = sA + sp * SLOT_U + wbU;
        ushort_t* dB = sB + sp * SLOT_U + wbU;
        stage16(A  + rowA0 + kk + g8, dA);
        stage16(BT + rowB0 + kk + g8, dB);
        stage16(A  + rowA1 + kk + g8, dA + 4096);
        stage16(BT + rowB1 + kk + g8, dB + 4096);
    }
    asm volatile("s_waitcnt vmcnt(8)" ::: "memory");
    __builtin_amdgcn_s_barrier();

    for (int s = 0; s < NT; ++s) {
        const ushort_t* sAs = sA + (s & 3) * SLOT_U;
        const ushort_t* sBs = sB + (s & 3) * SLOT_U;
        const int sp = s + 3;
        const int kk = sp << 5;
        ushort_t* dA = sA + (sp & 3) * SLOT_U + wbU;
        ushort_t* dB = sB + (sp & 3) * SLOT_U + wbU;

        // ---- phase A: read B0-3 + A0-3 (8 b128); stage issue-0 pair ----
        bf16x8 bR[4], aR[4];
#pragma unroll
        for (int n = 0; n < 4; ++n) bR[n] = *(const bf16x8*)(sBs + offB[n]);
#pragma unroll
        for (int m = 0; m < 4; ++m) aR[m] = *(const bf16x8*)(sAs + offA[m]);
        if (sp < NT) {
            stage16(A  + rowA0 + kk + g8, dA);
            stage16(BT + rowB0 + kk + g8, dB);
        }
        // no barrier / no blanket lgkm: compiler inserts fine-grained
        // lgkmcnt before each dependent MFMA.
        __builtin_amdgcn_s_setprio(1);
#pragma unroll
        for (int m = 0; m < 4; ++m)
#pragma unroll
            for (int n = 0; n < 4; ++n)
                acc[m][n] = __builtin_amdgcn_mfma_f32_16x16x32_bf16(
                    aR[m], bR[n], acc[m][n], 0, 0, 0);
        __builtin_amdgcn_s_setprio(0);

        // ---- phase B: read A4-7 (4 b128); stage issue-1 pair ----
        bf16x8 aS[4];
#pragma unroll
        for (int m = 0; m < 4; ++m) aS[m] = *(const bf16x8*)(sAs + offA[4 + m]);
        if (sp < NT) {
            stage16(A  + rowA1 + kk + g8, dA + 4096);
            stage16(BT + rowB1 + kk + g8, dB + 4096);
        }
        __builtin_amdgcn_s_setprio(1);
#pragma unroll
        for (int m = 0; m < 4; ++m)
#pragma unroll
            for (int n = 0; n < 4; ++n)
                acc[4 + m][n] = __builtin_amdgcn_mfma_f32_16x16x32_bf16(
                    aS[m], bR[n], acc[4 + m][n], 0, 0, 0);
        __builtin_amdgcn_s_setprio(0);

        // ---- slice boundary (ONLY barrier per slice): drain slice s+1,
        //      keep s+2/s+3 in flight; epilogue drains 8->4->0 ----
        if (s < NT - 3)       asm volatile("s_waitcnt vmcnt(8)" ::: "memory");
        else if (s == NT - 3) asm volatile("s_waitcnt vmcnt(4)" ::: "memory");
        else if (s == NT - 2) asm volatile("s_waitcnt vmcnt(0)" ::: "memory");
        __builtin_amdgcn_s_barrier();
    }

    // ---- epilogue: tanh+bias -> LDS C-stage (swizzled, conflict-free) ----
    // 16x16 C/D mapping: col=lane&15, row=(lane>>4)*4+reg [m89 verified].
    ushort_t* sC = smem;   // 256 x 256 bf16 = 128 KiB, exactly the ring
#pragma unroll
    for (int n = 0; n < 4; ++n) {
        const int cg  = wx * 64 + n * 16 + l15;
        const int col = bcol + cg;
        const int bidx = PERM_BIAS ? ((col & 511) * 17 + (col >> 9)) : col;
        const float bv = bias[bidx];
#pragma unroll
        for (int m = 0; m < 8; ++m) {
            const int rg0 = wy * 128 + m * 16 + kg * 4;       // 4-aligned
            const int cgs = cg ^ (((rg0 >> 2) & 3) << 4);     // quarter-disjoint
#pragma unroll
            for (int reg = 0; reg < 4; ++reg)
                sC[(rg0 + reg) * 256 + cgs] =
                    f2bf(fast_tanh(acc[m][n][reg] + bv));
        }
    }
    __syncthreads();

    // ---- readback: rows linear, 16B chunks un-permuted; nt 1KB stores ----
#pragma unroll
    for (int i = 0; i < 16; ++i) {
        const int slot = i * 512 + t;        // 8192 chunk-slots = 256 rows x 32
        const int r  = slot >> 5;
        const int j  = slot & 31;
        const int js = j ^ (((r >> 2) & 3) << 1);
        const i32x4 v = *(const i32x4*)(sC + r * 256 + js * 8);
        __builtin_nontemporal_store(
            v, (i32x4*)(C + (size_t)(brow + r) * N_ + bcol + j * 8));
    }
}

// ---------------------------------------------------------------------------
// Spline postprocess, plane-major net layout: net[b][p*512 + n] holds value
// p of unit n (p<9: h_net, p>=9: w_net). One block per batch row, 256
// threads; thread t handles units 2t, 2t+1 via dword plane loads (coalesced).
// nontemporal loads/stores (all data read/written exactly once).
// ---------------------------------------------------------------------------
__global__ __launch_bounds__(256) void spline_post(
    const ushort_t* __restrict__ net,   // rows x OUTD bf16, plane-major
    const float* __restrict__ v_in,     // rows x 2N
    const float* __restrict__ ld_in,    // rows
    float* __restrict__ v_out,          // rows x 2N
    float* __restrict__ ld_out)         // rows
{
    const int b = blockIdx.x;
    const int t = threadIdx.x;          // 0..255

    unsigned int pl[17];
    const ushort_t* base = net + (size_t)b * OUTD + 2 * t;
#pragma unroll
    for (int p = 0; p < 17; ++p)
        pl[p] = __builtin_nontemporal_load((const unsigned int*)(base + p * 512));

    {
        const f32x2v vp = __builtin_nontemporal_load(
            (const f32x2v*)(v_in + (size_t)b * (2 * NN) + 2 * t));
        __builtin_nontemporal_store(
            vp, (f32x2v*)(v_out + (size_t)b * (2 * NN) + 2 * t));
    }
    const f32x2v va2 = __builtin_nontemporal_load(
        (const f32x2v*)(v_in + (size_t)b * (2 * NN) + NN + 2 * t));

    float vact[2];
    float lt_sum = 0.f;
#pragma unroll 1
    for (int u = 0; u < 2; ++u) {
        const int sh = u * 16;
        float t17[17];
#pragma unroll
        for (int p = 0; p < 17; ++p)
            t17[p] = bf2f((ushort_t)(pl[p] >> sh));

        float m = t17[9];
#pragma unroll
        for (int i = 10; i < 17; i++) m = fmaxf(m, t17[i]);
        float wn[8], wsum = 0.f;
#pragma unroll
        for (int i = 0; i < 8; i++) { wn[i] = __expf(t17[9 + i] - m); wsum += wn[i]; }
        const float winv = 1.f / wsum;
#pragma unroll
        for (int i = 0; i < 8; i++) wn[i] *= winv;

        float eh[9];
#pragma unroll
        for (int i = 0; i < 9; i++) eh[i] = __expf(t17[i]);
        float denom = 0.f;
#pragma unroll
        for (int k = 0; k < 8; k++) denom += 0.5f * wn[k] * (eh[k] + eh[k + 1]);
        const float dinv = 1.f / denom;
        float hn[9];
#pragma unroll
        for (int i = 0; i < 9; i++) hn[i] = eh[i] * dinv;

        float kx[9], ky[9];
        kx[0] = 0.f; ky[0] = 0.f;
#pragma unroll
        for (int k = 0; k < 8; k++) {
            kx[k + 1] = kx[k] + wn[k];
            ky[k + 1] = ky[k] + 0.5f * wn[k] * (hn[k] + hn[k + 1]);
        }

        const float va = (u == 0) ? va2.x : va2.y;
        int cnt = 0;
#pragma unroll
        for (int j = 0; j < 9; j++) cnt += (kx[j] < va) ? 1 : 0;
        int k = cnt - 1;
        k = k < 0 ? 0 : (k > KKN - 1 ? KKN - 1 : k);

        const float wseg = wn[k];
        const float hlo = hn[k], hhi = hn[k + 1];
        const float xlo = kx[k], ylo = ky[k];
        const float alpha = (va - xlo) / wseg;
        vact[u] = ylo + alpha * hlo * wseg + 0.5f * alpha * alpha * (hhi - hlo) * wseg;
        lt_sum += __logf(hlo + alpha * (hhi - hlo));
    }

    {
        f32x2v vo; vo.x = vact[0]; vo.y = vact[1];
        __builtin_nontemporal_store(
            vo, (f32x2v*)(v_out + (size_t)b * (2 * NN) + NN + 2 * t));
    }

    __shared__ float wred[4];
#pragma unroll
    for (int o = 32; o > 0; o >>= 1) lt_sum += __shfl_down(lt_sum, o, 64);
    if ((t & 63) == 0) wred[t >> 6] = lt_sum;
    __syncthreads();
    if (t == 0)
        ld_out[b] = ld_in[b] - (wred[0] + wred[1] + wred[2] + wred[3]);
}

// ---------------------------------------------------------------------------
extern "C" void kernel_launch(void* const* d_in, const int* in_sizes, int n_in,
                              void* d_out, int out_size, void* d_ws, size_t ws_size,
                              hipStream_t stream)
{
    const float* v_in = (const float*)d_in[0];   // B x 2N
    const float* ld   = (const float*)d_in[1];   // B x 1
    const float* W1   = (const float*)d_in[2];   // N x H
    const float* b1   = (const float*)d_in[3];   // H
    const float* W2   = (const float*)d_in[4];   // H x H
    const float* b2   = (const float*)d_in[5];   // H
    const float* W3   = (const float*)d_in[6];   // H x OUTD
    const float* b3   = (const float*)d_in[7];   // OUTD

    float* out    = (float*)d_out;
    float* v_out  = out;                           // B*2N
    float* ld_out = out + (size_t)BB * (2 * NN);   // B

    // Workspace tiers (R3-verified: full tier 172Mi fits):
    //   [0, region)       chunk net buffer (plane-major); a0b + x1b alias here
    //   [region, +16Mi)   x2b ; then W1T (1Mi) W2T (2Mi) W3T (17Mi)
    const size_t Mi = 1048576;
    int    chunk;
    size_t region;
    if      (ws_size >= 172 * Mi) { chunk = 8192; region = 136 * Mi; }
    else if (ws_size >= 104 * Mi) { chunk = 4096; region =  68 * Mi; }
    else if (ws_size >=  70 * Mi) { chunk = 2048; region =  34 * Mi; }
    else                          { chunk = 1024; region =  24 * Mi; }

    char* ws = (char*)d_ws;
    ushort_t* a0b = (ushort_t*)(ws);
    ushort_t* x1b = (ushort_t*)(ws + 8 * Mi);
    ushort_t* netc = (ushort_t*)(ws);                       // chunk buffer
    ushort_t* x2b = (ushort_t*)(ws + region);
    ushort_t* W1T = (ushort_t*)(ws + region + 16 * Mi);
    ushort_t* W2T = (ushort_t*)(ws + region + 17 * Mi);
    ushort_t* W3T = (ushort_t*)(ws + region + 19 * Mi);

    // conversions
    conv_v<<<dim3(BB * NN / 2 / 256), dim3(256), 0, stream>>>(v_in, a0b);
    transpose_cvt<false><<<dim3(HH / 32, NN / 32),   dim3(32, 8), 0, stream>>>(W1, W1T, NN, HH);
    transpose_cvt<false><<<dim3(HH / 32, HH / 32),   dim3(32, 8), 0, stream>>>(W2, W2T, HH, HH);
    transpose_cvt<true ><<<dim3(OUTD / 32, HH / 32), dim3(32, 8), 0, stream>>>(W3, W3T, HH, OUTD);

    // GEMM1: x1 = tanh((v_passive-0.5) @ W1 + b1)   M=8192 N=1024 K=512
    gemm_bt_tanh<false><<<dim3(HH / 128, BB / 128), dim3(256), 0, stream>>>(
        a0b, W1T, b1, x1b, HH, NN);
    // GEMM2: x2 = tanh(x1 @ W2 + b2)                M=8192 N=1024 K=1024
    gemm_bt_tanh<false><<<dim3(HH / 128, BB / 128), dim3(256), 0, stream>>>(
        x1b, W2T, b2, x2b, HH, HH);

    // GEMM3 + spline, chunked (single pass when chunk==8192)
    // R11: de-serialized schedule (1 barrier/slice).
    for (int c = 0; c < BB / chunk; ++c) {
        const ushort_t* xa = x2b + (size_t)c * chunk * HH;
        gemm3_bt_tanh_256<true><<<dim3(OUTD / 256, chunk / 256), dim3(512), 0, stream>>>(
            xa, W3T, b3, netc, OUTD, HH);
        spline_post<<<dim3(chunk), dim3(256), 0, stream>>>(
            netc,
            v_in   + (size_t)c * chunk * (2 * NN),
            ld     + (size_t)c * chunk,
            v_out  + (size_t)c * chunk * (2 * NN),
            ld_out + (size_t)c * chunk);
    }
}